// Round 1
// baseline (46774.612 us; speedup 1.0000x reference)
//
#include <hip/hip_runtime.h>
#include <hip/hip_bf16.h>

#define TPB 256

// ---------------- conv1: (512,1,28,28) -> (512,64,26,26), 3x3, pad0, +bias ----
__global__ void conv1_k(const float* __restrict__ x, const float* __restrict__ w,
                        const float* __restrict__ b, float* __restrict__ out) {
    int idx = blockIdx.x * TPB + threadIdx.x;
    const int total = 512 * 64 * 26 * 26;
    if (idx >= total) return;
    int ox = idx % 26; int t = idx / 26;
    int oy = t % 26;   t /= 26;
    int co = t % 64;   int n = t / 64;
    const float* xp = x + (size_t)n * 784 + oy * 28 + ox;
    const float* wp = w + co * 9;
    float s = b[co];
#pragma unroll
    for (int ky = 0; ky < 3; ky++)
#pragma unroll
        for (int kx = 0; kx < 3; kx++)
            s += xp[ky * 28 + kx] * wp[ky * 3 + kx];
    out[idx] = s;
}

// ---------------- GroupNorm stats: one wave per (n,g) -------------------------
__global__ void gn_stats_k(const float* __restrict__ x, float* __restrict__ mean,
                           float* __restrict__ rstd, int N, int C, int HW, int G) {
    int gid  = (blockIdx.x * blockDim.x + threadIdx.x) >> 6;
    int lane = threadIdx.x & 63;
    int total = N * G;
    if (gid >= total) return;
    int n = gid / G, g = gid % G;
    int cpg = C / G;
    int gsize = cpg * HW;
    const float* p = x + ((size_t)n * C + (size_t)g * cpg) * HW;
    float s = 0.f, s2 = 0.f;
    for (int i = lane; i < gsize; i += 64) { float v = p[i]; s += v; s2 += v * v; }
#pragma unroll
    for (int off = 32; off; off >>= 1) {
        s  += __shfl_down(s,  off);
        s2 += __shfl_down(s2, off);
    }
    if (lane == 0) {
        float m = s / gsize;
        float var = s2 / gsize - m * m;
        mean[gid] = m;
        rstd[gid] = rsqrtf(var + 1e-5f);
    }
}

// ---------------- GroupNorm apply + ReLU (in-place ok: in may == out) ---------
__global__ void gn_apply_relu_k(const float* __restrict__ x, float* __restrict__ out,
                                const float* __restrict__ mean, const float* __restrict__ rstd,
                                const float* __restrict__ gw, const float* __restrict__ gb,
                                int N, int C, int HW, int G) {
    int idx = blockIdx.x * TPB + threadIdx.x;
    int total = N * C * HW;
    if (idx >= total) return;
    int c = (idx / HW) % C;
    int n = idx / (HW * C);
    int cpg = C / G;
    int g = c / cpg;
    float m = mean[n * G + g], r = rstd[n * G + g];
    float v = (x[idx] - m) * r * gw[c] + gb[c];
    out[idx] = v > 0.f ? v : 0.f;
}

// ---------------- generic 3x3 conv, C=64->64, pad=1, stride s, optional add --
__global__ void conv3x3_k(const float* __restrict__ in, const float* __restrict__ w,
                          const float* __restrict__ addend, float* __restrict__ out,
                          int N, int H, int W, int OH, int OW, int stride) {
    int idx = blockIdx.x * TPB + threadIdx.x;
    int total = N * 64 * OH * OW;
    if (idx >= total) return;
    int ox = idx % OW; int t = idx / OW;
    int oy = t % OH;   t /= OH;
    int co = t % 64;   int n = t / 64;
    int iy0 = oy * stride - 1, ix0 = ox * stride - 1;
    const float* wp = w + co * 576;
    const float* ip = in + (size_t)n * 64 * H * W;
    float s = addend ? addend[idx] : 0.f;
    for (int ci = 0; ci < 64; ci++) {
        const float* ipc = ip + ci * H * W;
        const float* wpc = wp + ci * 9;
#pragma unroll
        for (int ky = 0; ky < 3; ky++) {
            int iy = iy0 + ky;
            if ((unsigned)iy >= (unsigned)H) continue;
#pragma unroll
            for (int kx = 0; kx < 3; kx++) {
                int ix = ix0 + kx;
                if ((unsigned)ix >= (unsigned)W) continue;
                s += ipc[iy * W + ix] * wpc[ky * 3 + kx];
            }
        }
    }
    out[idx] = s;
}

// ---------------- 1x1 conv, stride 2, pad 0 ----------------------------------
__global__ void conv1x1s2_k(const float* __restrict__ in, const float* __restrict__ w,
                            float* __restrict__ out, int N, int H, int W, int OH, int OW) {
    int idx = blockIdx.x * TPB + threadIdx.x;
    int total = N * 64 * OH * OW;
    if (idx >= total) return;
    int ox = idx % OW; int t = idx / OW;
    int oy = t % OH;   t /= OH;
    int co = t % 64;   int n = t / 64;
    const float* ip = in + (size_t)n * 64 * H * W + (size_t)(oy * 2) * W + ox * 2;
    const float* wp = w + co * 64;
    float s = 0.f;
    for (int ci = 0; ci < 64; ci++) s += ip[(size_t)ci * H * W] * wp[ci];
    out[idx] = s;
}

// ---------------- dst = alpha*a + beta*b -------------------------------------
__global__ void combine2_k(float* __restrict__ dst, const float* __restrict__ a,
                           const float* __restrict__ b, float alpha, float beta, int total) {
    int idx = blockIdx.x * TPB + threadIdx.x;
    if (idx >= total) return;
    dst[idx] = alpha * a[idx] + beta * b[idx];
}

// ---------------- mean-pool (7x7) + FC: (512,64,7,7) -> (512,10) -------------
__global__ void pool_fc_k(const float* __restrict__ h, const float* __restrict__ fcw,
                          const float* __restrict__ fcb, float* __restrict__ out) {
    int n = blockIdx.x;
    int c = threadIdx.x;  // 64 threads
    __shared__ float pooled[64];
    const float* p = h + ((size_t)n * 64 + c) * 49;
    float s = 0.f;
#pragma unroll
    for (int i = 0; i < 49; i++) s += p[i];
    pooled[c] = s * (1.f / 49.f);
    __syncthreads();
    if (c < 10) {
        float acc = fcb[c];
#pragma unroll
        for (int k = 0; k < 64; k++) acc += pooled[k] * fcw[c * 64 + k];
        out[(size_t)n * 10 + c] = acc;
    }
}

static inline int nblk(long long total) { return (int)((total + TPB - 1) / TPB); }

extern "C" void kernel_launch(void* const* d_in, const int* in_sizes, int n_in,
                              void* d_out, int out_size, void* d_ws, size_t ws_size,
                              hipStream_t stream) {
    const float* x       = (const float*)d_in[0];
    const float* conv1_w = (const float*)d_in[1];
    const float* conv1_b = (const float*)d_in[2];
    const float* r1_g1w  = (const float*)d_in[3];
    const float* r1_g1b  = (const float*)d_in[4];
    const float* r1_c1w  = (const float*)d_in[5];
    const float* r1_g2w  = (const float*)d_in[6];
    const float* r1_g2b  = (const float*)d_in[7];
    const float* r1_c2w  = (const float*)d_in[8];
    const float* r1_dw   = (const float*)d_in[9];
    const float* r2_g1w  = (const float*)d_in[10];
    const float* r2_g1b  = (const float*)d_in[11];
    const float* r2_c1w  = (const float*)d_in[12];
    const float* r2_g2w  = (const float*)d_in[13];
    const float* r2_g2b  = (const float*)d_in[14];
    const float* r2_c2w  = (const float*)d_in[15];
    const float* r2_dw   = (const float*)d_in[16];
    const float* o_g1w   = (const float*)d_in[17];
    const float* o_g1b   = (const float*)d_in[18];
    const float* o_c1w   = (const float*)d_in[19];
    const float* o_g2w   = (const float*)d_in[20];
    const float* o_g2b   = (const float*)d_in[21];
    const float* o_c2w   = (const float*)d_in[22];
    const float* fin_gw  = (const float*)d_in[23];
    const float* fin_gb  = (const float*)d_in[24];
    const float* fc_w    = (const float*)d_in[25];
    const float* fc_b    = (const float*)d_in[26];
    float* out = (float*)d_out;

    const int N = 512;
    const long long SZ26 = 512LL * 64 * 26 * 26;
    const long long SZ13 = 512LL * 64 * 13 * 13;
    const long long SZ7  = 512LL * 64 * 7 * 7;

    float* B26  = (float*)d_ws;
    float* A13  = B26 + SZ26;
    float* B13  = A13 + SZ13;
    float* Z7   = B13 + SZ13;
    float* U7   = Z7 + SZ7;
    float* T1   = U7 + SZ7;
    float* T2   = T1 + SZ7;
    float* K7   = T2 + SZ7;
    float* ACC  = K7 + SZ7;
    float* MEAN = ACC + SZ7;
    float* RSTD = MEAN + 512 * 64;

    // helper: GroupNorm(+ReLU) src -> dst (src may == dst)
    auto gn = [&](const float* src, float* dst, int HW, int G,
                  const float* gw, const float* gb) {
        int waves = N * G;
        gn_stats_k<<<nblk((long long)waves * 64), TPB, 0, stream>>>(src, MEAN, RSTD, N, 64, HW, G);
        gn_apply_relu_k<<<nblk((long long)N * 64 * HW), TPB, 0, stream>>>(
            src, dst, MEAN, RSTD, gw, gb, N, 64, HW, G);
    };

    // ---- stage 0: conv1 ----
    conv1_k<<<nblk(SZ26), TPB, 0, stream>>>(x, conv1_w, conv1_b, B26);

    // ---- residual block 1: 26x26 -> 13x13 ----
    gn(B26, B26, 676, 32, r1_g1w, r1_g1b);                               // h = relu(gn(x))
    conv3x3_k<<<nblk(SZ13), TPB, 0, stream>>>(B26, r1_c1w, nullptr, A13,
                                              N, 26, 26, 13, 13, 2);     // main s2
    conv1x1s2_k<<<nblk(SZ13), TPB, 0, stream>>>(B26, r1_dw, B13, N, 26, 26, 13, 13); // skip
    gn(A13, A13, 169, 32, r1_g2w, r1_g2b);
    conv3x3_k<<<nblk(SZ13), TPB, 0, stream>>>(A13, r1_c2w, B13, B13,
                                              N, 13, 13, 13, 13, 1);     // + skip -> B13

    // ---- residual block 2: 13x13 -> 7x7 ----
    gn(B13, B13, 169, 32, r2_g1w, r2_g1b);
    conv3x3_k<<<nblk(SZ7), TPB, 0, stream>>>(B13, r2_c1w, nullptr, U7,
                                             N, 13, 13, 7, 7, 2);
    conv1x1s2_k<<<nblk(SZ7), TPB, 0, stream>>>(B13, r2_dw, Z7, N, 13, 13, 7, 7);
    gn(U7, U7, 49, 32, r2_g2w, r2_g2b);
    conv3x3_k<<<nblk(SZ7), TPB, 0, stream>>>(U7, r2_c2w, Z7, Z7,
                                             N, 7, 7, 7, 7, 1);          // z0 -> Z7

    // ---- ODE: RK4, 12 steps, dt = 0.5 ----
    const float dt = 6.0f / 12.0f;
    auto odefunc = [&](const float* src, float* kdst) {
        gn(src, T1, 49, 64, o_g1w, o_g1b);
        conv3x3_k<<<nblk(SZ7), TPB, 0, stream>>>(T1, o_c1w, nullptr, T2,
                                                 N, 7, 7, 7, 7, 1);
        gn(T2, T2, 49, 64, o_g2w, o_g2b);
        conv3x3_k<<<nblk(SZ7), TPB, 0, stream>>>(T2, o_c2w, src, kdst,
                                                 N, 7, 7, 7, 7, 1);      // + src
    };
    int eb = nblk(SZ7);
    for (int step = 0; step < 12; step++) {
        odefunc(Z7, K7);                                                          // k1
        combine2_k<<<eb, TPB, 0, stream>>>(ACC, K7, K7, 1.f, 0.f, (int)SZ7);      // acc = k1
        combine2_k<<<eb, TPB, 0, stream>>>(U7, Z7, K7, 1.f, 0.5f * dt, (int)SZ7); // u = z + dt/2 k1
        odefunc(U7, K7);                                                          // k2
        combine2_k<<<eb, TPB, 0, stream>>>(ACC, ACC, K7, 1.f, 2.f, (int)SZ7);
        combine2_k<<<eb, TPB, 0, stream>>>(U7, Z7, K7, 1.f, 0.5f * dt, (int)SZ7);
        odefunc(U7, K7);                                                          // k3
        combine2_k<<<eb, TPB, 0, stream>>>(ACC, ACC, K7, 1.f, 2.f, (int)SZ7);
        combine2_k<<<eb, TPB, 0, stream>>>(U7, Z7, K7, 1.f, dt, (int)SZ7);
        odefunc(U7, K7);                                                          // k4
        combine2_k<<<eb, TPB, 0, stream>>>(ACC, ACC, K7, 1.f, 1.f, (int)SZ7);
        combine2_k<<<eb, TPB, 0, stream>>>(Z7, Z7, ACC, 1.f, dt / 6.f, (int)SZ7); // z += dt/6 acc
    }

    // ---- final: gn32 + relu, pool, fc ----
    gn(Z7, T1, 49, 32, fin_gw, fin_gb);
    pool_fc_k<<<512, 64, 0, stream>>>(T1, fc_w, fc_b, out);
}

// Round 2
// 8686.720 us; speedup vs baseline: 5.3846x; 5.3846x over previous
//
#include <hip/hip_runtime.h>
#include <hip/hip_bf16.h>

#define TPB 256

// ======================= prologue kernels (unchanged) ========================

__global__ void conv1_k(const float* __restrict__ x, const float* __restrict__ w,
                        const float* __restrict__ b, float* __restrict__ out) {
    int idx = blockIdx.x * TPB + threadIdx.x;
    const int total = 512 * 64 * 26 * 26;
    if (idx >= total) return;
    int ox = idx % 26; int t = idx / 26;
    int oy = t % 26;   t /= 26;
    int co = t % 64;   int n = t / 64;
    const float* xp = x + (size_t)n * 784 + oy * 28 + ox;
    const float* wp = w + co * 9;
    float s = b[co];
#pragma unroll
    for (int ky = 0; ky < 3; ky++)
#pragma unroll
        for (int kx = 0; kx < 3; kx++)
            s += xp[ky * 28 + kx] * wp[ky * 3 + kx];
    out[idx] = s;
}

__global__ void gn_stats_k(const float* __restrict__ x, float* __restrict__ mean,
                           float* __restrict__ rstd, int N, int C, int HW, int G) {
    int gid  = (blockIdx.x * blockDim.x + threadIdx.x) >> 6;
    int lane = threadIdx.x & 63;
    int total = N * G;
    if (gid >= total) return;
    int n = gid / G, g = gid % G;
    int cpg = C / G;
    int gsize = cpg * HW;
    const float* p = x + ((size_t)n * C + (size_t)g * cpg) * HW;
    float s = 0.f, s2 = 0.f;
    for (int i = lane; i < gsize; i += 64) { float v = p[i]; s += v; s2 += v * v; }
#pragma unroll
    for (int off = 32; off; off >>= 1) {
        s  += __shfl_down(s,  off);
        s2 += __shfl_down(s2, off);
    }
    if (lane == 0) {
        float m = s / gsize;
        float var = s2 / gsize - m * m;
        mean[gid] = m;
        rstd[gid] = rsqrtf(var + 1e-5f);
    }
}

__global__ void gn_apply_relu_k(const float* __restrict__ x, float* __restrict__ out,
                                const float* __restrict__ mean, const float* __restrict__ rstd,
                                const float* __restrict__ gw, const float* __restrict__ gb,
                                int N, int C, int HW, int G) {
    int idx = blockIdx.x * TPB + threadIdx.x;
    int total = N * C * HW;
    if (idx >= total) return;
    int c = (idx / HW) % C;
    int n = idx / (HW * C);
    int cpg = C / G;
    int g = c / cpg;
    float m = mean[n * G + g], r = rstd[n * G + g];
    float v = (x[idx] - m) * r * gw[c] + gb[c];
    out[idx] = v > 0.f ? v : 0.f;
}

__global__ void conv3x3_k(const float* __restrict__ in, const float* __restrict__ w,
                          const float* __restrict__ addend, float* __restrict__ out,
                          int N, int H, int W, int OH, int OW, int stride) {
    int idx = blockIdx.x * TPB + threadIdx.x;
    int total = N * 64 * OH * OW;
    if (idx >= total) return;
    int ox = idx % OW; int t = idx / OW;
    int oy = t % OH;   t /= OH;
    int co = t % 64;   int n = t / 64;
    int iy0 = oy * stride - 1, ix0 = ox * stride - 1;
    const float* wp = w + co * 576;
    const float* ip = in + (size_t)n * 64 * H * W;
    float s = addend ? addend[idx] : 0.f;
    for (int ci = 0; ci < 64; ci++) {
        const float* ipc = ip + ci * H * W;
        const float* wpc = wp + ci * 9;
#pragma unroll
        for (int ky = 0; ky < 3; ky++) {
            int iy = iy0 + ky;
            if ((unsigned)iy >= (unsigned)H) continue;
#pragma unroll
            for (int kx = 0; kx < 3; kx++) {
                int ix = ix0 + kx;
                if ((unsigned)ix >= (unsigned)W) continue;
                s += ipc[iy * W + ix] * wpc[ky * 3 + kx];
            }
        }
    }
    out[idx] = s;
}

__global__ void conv1x1s2_k(const float* __restrict__ in, const float* __restrict__ w,
                            float* __restrict__ out, int N, int H, int W, int OH, int OW) {
    int idx = blockIdx.x * TPB + threadIdx.x;
    int total = N * 64 * OH * OW;
    if (idx >= total) return;
    int ox = idx % OW; int t = idx / OW;
    int oy = t % OH;   t /= OH;
    int co = t % 64;   int n = t / 64;
    const float* ip = in + (size_t)n * 64 * H * W + (size_t)(oy * 2) * W + ox * 2;
    const float* wp = w + co * 64;
    float s = 0.f;
    for (int ci = 0; ci < 64; ci++) s += ip[(size_t)ci * H * W] * wp[ci];
    out[idx] = s;
}

// ======================= ODE mega-kernel =====================================
// Block = one image. 256 threads = 4 waves. Entire 12-step RK4 + final
// GN(32)+pool+FC in one launch. All state in LDS.
//
// Conv thread map: cb = t>>4 (16 co-blocks of 4 channels), slot = t&15,
// row = slot>>1 (0..6, slots 14/15 idle), half = slot&1 (cols 0-3 / 4-6).
// Weights pre-transposed to wT[wave][ci][co_local][12] so each wave stages
// its 16-co slice per 2-ci chunk into private LDS (no block barrier).

#define KC 2
#define H_PITCH 12
#define H_CH (7 * H_PITCH)                 // 84 floats per channel plane
#define WCHUNK (KC * 16 * H_PITCH)         // 384 floats per wave chunk
#define WREGION (64 * 16 * H_PITCH)        // 12288 floats per wave

__global__ void wprep_k(const float* __restrict__ w, float* __restrict__ wT) {
    int i = blockIdx.x * TPB + threadIdx.x;
    if (i >= 64 * 64 * 12) return;
    int k = i % 12; int r = i / 12;
    int col = r % 16; r /= 16;
    int ci = r % 64; int wave = r / 64;
    int co = wave * 16 + col;
    wT[i] = (k < 9) ? w[(co * 64 + ci) * 9 + k] : 0.f;
}

__global__ __launch_bounds__(256, 2)
void ode_mega_k(const float* __restrict__ z0g,
                const float* __restrict__ wT1, const float* __restrict__ wT2,
                const float* __restrict__ g1w, const float* __restrict__ g1b,
                const float* __restrict__ g2w, const float* __restrict__ g2b,
                const float* __restrict__ fgw, const float* __restrict__ fgb,
                const float* __restrict__ fcw, const float* __restrict__ fcb,
                float* __restrict__ out) {
    __shared__ float smem[4 * 3136 + 64 * H_CH + 4 * WCHUNK + 64];
    float* zb0 = smem;
    float* zb1 = smem + 3136;
    float* ub  = smem + 2 * 3136;
    float* h2  = smem + 3 * 3136;
    float* h   = smem + 4 * 3136;
    float* wl  = smem + 4 * 3136 + 64 * H_CH;
    float* pooled = wl + 4 * WCHUNK;

    const int t = threadIdx.x;
    const int n = blockIdx.x;
    const int c4 = t >> 2, q4 = t & 3;          // GN map: 4 threads / channel
    const int wave = t >> 6, lane = t & 63;
    const int cb = t >> 4, cbl = cb & 3, slot = t & 15;
    const int row = slot >> 1, half = slot & 1;
    const int co0 = cb * 4;
    float* wlw = wl + wave * WCHUNK;

    const float g1wv = g1w[c4], g1bv = g1b[c4];
    const float g2wv = g2w[c4], g2bv = g2b[c4];

    // ---- init: load z0, zero h (halo cols stay 0 forever) ----
    for (int i = t; i < 3136; i += 256) zb0[i] = z0g[(size_t)n * 3136 + i];
    for (int i = t; i < 64 * H_CH; i += 256) h[i] = 0.f;
    __syncthreads();

    // ---- GN(groups=64) + ReLU: src[64*49] -> h (halo layout) ----
    auto gn64 = [&](const float* sp, float gwv, float gbv) {
        float v[13], s = 0.f, s2 = 0.f;
#pragma unroll
        for (int i = 0; i < 13; i++) {
            int p = q4 + i * 4;
            float x = (p < 49) ? sp[c4 * 49 + p] : 0.f;
            v[i] = x; s += x; s2 += x * x;
        }
        s += __shfl_xor(s, 1); s2 += __shfl_xor(s2, 1);
        s += __shfl_xor(s, 2); s2 += __shfl_xor(s2, 2);
        float m = s * (1.f / 49.f);
        float r = rsqrtf(s2 * (1.f / 49.f) - m * m + 1e-5f);
        float sc = r * gwv, sh = gbv - m * sc;
#pragma unroll
        for (int i = 0; i < 13; i++) {
            int p = q4 + i * 4;
            if (p < 49) {
                float y = fmaxf(v[i] * sc + sh, 0.f);
                h[(c4 * 7 + p / 7) * H_PITCH + (p % 7) + 1] = y;
            }
        }
    };

    // ---- conv 3x3 64->64 over h; epilogue by mode ----
    // mode 0: h2 = conv.  mode 1: k = conv + src; znew (+)= ck*k; u = z + cu*k
    auto convf = [&](const float* __restrict__ wT, int mode, int e, float ckv, float cuv,
                     const float* __restrict__ src, const float* __restrict__ zp,
                     float* __restrict__ znew) {
        const float* wg = wT + (size_t)wave * WREGION;
        float acc[4][4];
#pragma unroll
        for (int j = 0; j < 4; j++)
#pragma unroll
            for (int px = 0; px < 4; px++) acc[j][px] = 0.f;

        // prefetch chunk 0 (6 floats / lane)
        float2 s0, s1, s2v;
        {
            const float2* gp = (const float2*)wg + lane * 3;
            s0 = gp[0]; s1 = gp[1]; s2v = gp[2];
        }
        for (int ch = 0; ch < 64 / KC; ch++) {
            {   // stage current chunk into this wave's LDS slice
                float2* wp = (float2*)wlw + lane * 3;
                wp[0] = s0; wp[1] = s1; wp[2] = s2v;
            }
            if (ch < 64 / KC - 1) {  // prefetch next chunk
                const float2* gp = (const float2*)(wg + (ch + 1) * WCHUNK) + lane * 3;
                s0 = gp[0]; s1 = gp[1]; s2v = gp[2];
            }
            // weights LDS -> regs (broadcast across the 16 threads per co)
            float wr[KC][4][9];
#pragma unroll
            for (int c2 = 0; c2 < KC; c2++)
#pragma unroll
                for (int j = 0; j < 4; j++) {
                    const float* wp2 = wlw + (c2 * 16 + cbl * 4 + j) * H_PITCH;
#pragma unroll
                    for (int k = 0; k < 9; k++) wr[c2][j][k] = wp2[k];
                }
#pragma unroll
            for (int c2 = 0; c2 < KC; c2++) {
                const float* hc = h + (ch * KC + c2) * H_CH + half * 4;
                float r0[6], r1[6], r2[6];
                {
                    int ry = row - 1;
                    if ((unsigned)ry < 7u) {
                        float4 a = *(const float4*)(hc + ry * H_PITCH);
                        float2 b = *(const float2*)(hc + ry * H_PITCH + 4);
                        r0[0]=a.x; r0[1]=a.y; r0[2]=a.z; r0[3]=a.w; r0[4]=b.x; r0[5]=b.y;
                    } else { r0[0]=r0[1]=r0[2]=r0[3]=r0[4]=r0[5]=0.f; }
                }
                {
                    int ry = row;
                    if ((unsigned)ry < 7u) {
                        float4 a = *(const float4*)(hc + ry * H_PITCH);
                        float2 b = *(const float2*)(hc + ry * H_PITCH + 4);
                        r1[0]=a.x; r1[1]=a.y; r1[2]=a.z; r1[3]=a.w; r1[4]=b.x; r1[5]=b.y;
                    } else { r1[0]=r1[1]=r1[2]=r1[3]=r1[4]=r1[5]=0.f; }
                }
                {
                    int ry = row + 1;
                    if ((unsigned)ry < 7u) {
                        float4 a = *(const float4*)(hc + ry * H_PITCH);
                        float2 b = *(const float2*)(hc + ry * H_PITCH + 4);
                        r2[0]=a.x; r2[1]=a.y; r2[2]=a.z; r2[3]=a.w; r2[4]=b.x; r2[5]=b.y;
                    } else { r2[0]=r2[1]=r2[2]=r2[3]=r2[4]=r2[5]=0.f; }
                }
#pragma unroll
                for (int j = 0; j < 4; j++) {
#pragma unroll
                    for (int px = 0; px < 4; px++) {
                        float s = acc[j][px];
                        s = fmaf(r0[px + 0], wr[c2][j][0], s);
                        s = fmaf(r0[px + 1], wr[c2][j][1], s);
                        s = fmaf(r0[px + 2], wr[c2][j][2], s);
                        s = fmaf(r1[px + 0], wr[c2][j][3], s);
                        s = fmaf(r1[px + 1], wr[c2][j][4], s);
                        s = fmaf(r1[px + 2], wr[c2][j][5], s);
                        s = fmaf(r2[px + 0], wr[c2][j][6], s);
                        s = fmaf(r2[px + 1], wr[c2][j][7], s);
                        s = fmaf(r2[px + 2], wr[c2][j][8], s);
                        acc[j][px] = s;
                    }
                }
            }
        }
        if (slot < 14) {
#pragma unroll
            for (int j = 0; j < 4; j++)
#pragma unroll
                for (int px = 0; px < 4; px++) {
                    int col = half * 4 + px;
                    if (col < 7) {
                        int idx = (co0 + j) * 49 + row * 7 + col;
                        if (mode == 0) {
                            h2[idx] = acc[j][px];
                        } else {
                            float kv = acc[j][px] + src[idx];
                            float zi = zp[idx];
                            if (e == 0) znew[idx] = zi + ckv * kv;
                            else        znew[idx] += ckv * kv;
                            if (e < 3)  ub[idx] = zi + cuv * kv;
                        }
                    }
                }
        }
    };

    // ---- RK4 loop ----
    float* z = zb0; float* znew = zb1;
    const float dt = 0.5f;
    for (int step = 0; step < 12; step++) {
        for (int e = 0; e < 4; e++) {
            float ckv = (e == 0 || e == 3) ? dt / 6.f : dt / 3.f;
            float cuv = (e == 2) ? dt : dt * 0.5f;
            const float* src = (e == 0) ? z : ub;
            gn64(src, g1wv, g1bv);
            __syncthreads();
            convf(wT1, 0, 0, 0.f, 0.f, nullptr, nullptr, nullptr);
            __syncthreads();
            gn64(h2, g2wv, g2bv);
            __syncthreads();
            convf(wT2, 1, e, ckv, cuv, src, z, znew);
            __syncthreads();
        }
        float* tmp = z; z = znew; znew = tmp;
    }

    // ---- final GN(groups=32) + ReLU + mean-pool ----
    {
        float v[13], s = 0.f, s2 = 0.f;
#pragma unroll
        for (int i = 0; i < 13; i++) {
            int p = q4 + i * 4;
            float x = (p < 49) ? z[c4 * 49 + p] : 0.f;
            v[i] = x; s += x; s2 += x * x;
        }
        s += __shfl_xor(s, 1); s2 += __shfl_xor(s2, 1);
        s += __shfl_xor(s, 2); s2 += __shfl_xor(s2, 2);
        s += __shfl_xor(s, 4); s2 += __shfl_xor(s2, 4);   // channel pair (G=32)
        float m = s * (1.f / 98.f);
        float r = rsqrtf(s2 * (1.f / 98.f) - m * m + 1e-5f);
        float sc = r * fgw[c4], sh = fgb[c4] - m * sc;
        float ps = 0.f;
#pragma unroll
        for (int i = 0; i < 13; i++) {
            int p = q4 + i * 4;
            if (p < 49) ps += fmaxf(v[i] * sc + sh, 0.f);
        }
        ps += __shfl_xor(ps, 1);
        ps += __shfl_xor(ps, 2);
        if (q4 == 0) pooled[c4] = ps * (1.f / 49.f);
    }
    __syncthreads();
    if (t < 10) {
        float a = fcb[t];
#pragma unroll
        for (int k = 0; k < 64; k++) a += pooled[k] * fcw[t * 64 + k];
        out[(size_t)n * 10 + t] = a;
    }
}

static inline int nblk(long long total) { return (int)((total + TPB - 1) / TPB); }

extern "C" void kernel_launch(void* const* d_in, const int* in_sizes, int n_in,
                              void* d_out, int out_size, void* d_ws, size_t ws_size,
                              hipStream_t stream) {
    const float* x       = (const float*)d_in[0];
    const float* conv1_w = (const float*)d_in[1];
    const float* conv1_b = (const float*)d_in[2];
    const float* r1_g1w  = (const float*)d_in[3];
    const float* r1_g1b  = (const float*)d_in[4];
    const float* r1_c1w  = (const float*)d_in[5];
    const float* r1_g2w  = (const float*)d_in[6];
    const float* r1_g2b  = (const float*)d_in[7];
    const float* r1_c2w  = (const float*)d_in[8];
    const float* r1_dw   = (const float*)d_in[9];
    const float* r2_g1w  = (const float*)d_in[10];
    const float* r2_g1b  = (const float*)d_in[11];
    const float* r2_c1w  = (const float*)d_in[12];
    const float* r2_g2w  = (const float*)d_in[13];
    const float* r2_g2b  = (const float*)d_in[14];
    const float* r2_c2w  = (const float*)d_in[15];
    const float* r2_dw   = (const float*)d_in[16];
    const float* o_g1w   = (const float*)d_in[17];
    const float* o_g1b   = (const float*)d_in[18];
    const float* o_c1w   = (const float*)d_in[19];
    const float* o_g2w   = (const float*)d_in[20];
    const float* o_g2b   = (const float*)d_in[21];
    const float* o_c2w   = (const float*)d_in[22];
    const float* fin_gw  = (const float*)d_in[23];
    const float* fin_gb  = (const float*)d_in[24];
    const float* fc_w    = (const float*)d_in[25];
    const float* fc_b    = (const float*)d_in[26];
    float* out = (float*)d_out;

    const int N = 512;
    const long long SZ26 = 512LL * 64 * 26 * 26;
    const long long SZ13 = 512LL * 64 * 13 * 13;
    const long long SZ7  = 512LL * 64 * 7 * 7;

    float* B26  = (float*)d_ws;
    float* A13  = B26 + SZ26;
    float* B13  = A13 + SZ13;
    float* Z7   = B13 + SZ13;
    float* U7   = Z7 + SZ7;
    float* MEAN = U7 + SZ7;
    float* RSTD = MEAN + 512 * 64;
    float* WT1  = RSTD + 512 * 64;
    float* WT2  = WT1 + 64 * 64 * 12;

    auto gn = [&](const float* src, float* dst, int HW, int G,
                  const float* gw, const float* gb) {
        int waves = N * G;
        gn_stats_k<<<nblk((long long)waves * 64), TPB, 0, stream>>>(src, MEAN, RSTD, N, 64, HW, G);
        gn_apply_relu_k<<<nblk((long long)N * 64 * HW), TPB, 0, stream>>>(
            src, dst, MEAN, RSTD, gw, gb, N, 64, HW, G);
    };

    // ---- weight prep for ODE convs ----
    wprep_k<<<nblk(64 * 64 * 12), TPB, 0, stream>>>(o_c1w, WT1);
    wprep_k<<<nblk(64 * 64 * 12), TPB, 0, stream>>>(o_c2w, WT2);

    // ---- stage 0: conv1 ----
    conv1_k<<<nblk(SZ26), TPB, 0, stream>>>(x, conv1_w, conv1_b, B26);

    // ---- residual block 1: 26x26 -> 13x13 ----
    gn(B26, B26, 676, 32, r1_g1w, r1_g1b);
    conv3x3_k<<<nblk(SZ13), TPB, 0, stream>>>(B26, r1_c1w, nullptr, A13,
                                              N, 26, 26, 13, 13, 2);
    conv1x1s2_k<<<nblk(SZ13), TPB, 0, stream>>>(B26, r1_dw, B13, N, 26, 26, 13, 13);
    gn(A13, A13, 169, 32, r1_g2w, r1_g2b);
    conv3x3_k<<<nblk(SZ13), TPB, 0, stream>>>(A13, r1_c2w, B13, B13,
                                              N, 13, 13, 13, 13, 1);

    // ---- residual block 2: 13x13 -> 7x7 ----
    gn(B13, B13, 169, 32, r2_g1w, r2_g1b);
    conv3x3_k<<<nblk(SZ7), TPB, 0, stream>>>(B13, r2_c1w, nullptr, U7,
                                             N, 13, 13, 7, 7, 2);
    conv1x1s2_k<<<nblk(SZ7), TPB, 0, stream>>>(B13, r2_dw, Z7, N, 13, 13, 7, 7);
    gn(U7, U7, 49, 32, r2_g2w, r2_g2b);
    conv3x3_k<<<nblk(SZ7), TPB, 0, stream>>>(U7, r2_c2w, Z7, Z7,
                                             N, 7, 7, 7, 7, 1);

    // ---- fused ODE (12 RK4 steps) + final GN + pool + FC ----
    ode_mega_k<<<512, 256, 0, stream>>>(Z7, WT1, WT2,
                                        o_g1w, o_g1b, o_g2w, o_g2b,
                                        fin_gw, fin_gb, fc_w, fc_b, out);
}

// Round 3
// 4742.890 us; speedup vs baseline: 9.8620x; 1.8315x over previous
//
#include <hip/hip_runtime.h>
#include <hip/hip_bf16.h>

#define TPB 256

#define KC 2
#define H_PITCH 12
#define H_CH (7 * H_PITCH)                 // 84 floats per channel plane
#define WCHUNK (KC * 16 * H_PITCH)         // 384 floats per wave chunk
#define WREGION (64 * 16 * H_PITCH)        // 12288 floats per wave

// ======================= small prologue kernels ==============================

__global__ void conv1_k(const float* __restrict__ x, const float* __restrict__ w,
                        const float* __restrict__ b, float* __restrict__ out) {
    int idx = blockIdx.x * TPB + threadIdx.x;
    const int total = 512 * 64 * 26 * 26;
    if (idx >= total) return;
    int ox = idx % 26; int t = idx / 26;
    int oy = t % 26;   t /= 26;
    int co = t % 64;   int n = t / 64;
    const float* xp = x + (size_t)n * 784 + oy * 28 + ox;
    const float* wp = w + co * 9;
    float s = b[co];
#pragma unroll
    for (int ky = 0; ky < 3; ky++)
#pragma unroll
        for (int kx = 0; kx < 3; kx++)
            s += xp[ky * 28 + kx] * wp[ky * 3 + kx];
    out[idx] = s;
}

__global__ void gn_stats_k(const float* __restrict__ x, float* __restrict__ mean,
                           float* __restrict__ rstd, int N, int C, int HW, int G) {
    int gid  = (blockIdx.x * blockDim.x + threadIdx.x) >> 6;
    int lane = threadIdx.x & 63;
    int total = N * G;
    if (gid >= total) return;
    int n = gid / G, g = gid % G;
    int cpg = C / G;
    int gsize = cpg * HW;
    const float* p = x + ((size_t)n * C + (size_t)g * cpg) * HW;
    float s = 0.f, s2 = 0.f;
    for (int i = lane; i < gsize; i += 64) { float v = p[i]; s += v; s2 += v * v; }
#pragma unroll
    for (int off = 32; off; off >>= 1) {
        s  += __shfl_down(s,  off);
        s2 += __shfl_down(s2, off);
    }
    if (lane == 0) {
        float m = s / gsize;
        float var = s2 / gsize - m * m;
        mean[gid] = m;
        rstd[gid] = rsqrtf(var + 1e-5f);
    }
}

__global__ void gn_apply_relu_k(const float* __restrict__ x, float* __restrict__ out,
                                const float* __restrict__ mean, const float* __restrict__ rstd,
                                const float* __restrict__ gw, const float* __restrict__ gb,
                                int N, int C, int HW, int G) {
    int idx = blockIdx.x * TPB + threadIdx.x;
    int total = N * C * HW;
    if (idx >= total) return;
    int c = (idx / HW) % C;
    int n = idx / (HW * C);
    int cpg = C / G;
    int g = c / cpg;
    float m = mean[n * G + g], r = rstd[n * G + g];
    float v = (x[idx] - m) * r * gw[c] + gb[c];
    out[idx] = v > 0.f ? v : 0.f;
}

// weight transpose: w[co][ci][3][3] -> wT[wave][ci][col16][12] (co = wave*16+col)
__global__ void wprep_k(const float* __restrict__ w, float* __restrict__ wT) {
    int i = blockIdx.x * TPB + threadIdx.x;
    if (i >= 64 * 64 * 12) return;
    int k = i % 12; int r = i / 12;
    int col = r % 16; r /= 16;
    int ci = r % 64; int wave = r / 64;
    int co = wave * 16 + col;
    wT[i] = (k < 9) ? w[(co * 64 + ci) * 9 + k] : 0.f;
}

// ======================= tiled 3x3 conv (prologue) ===========================
// Block = (image, 7x7 output tile). 256 threads. Input tile staged in LDS
// (zero-padded halo), weights streamed per-wave from pre-transposed wT.
// Thread map: cb = t>>4 (16 co-blocks of 4), slot = t&15, row = slot>>1,
// half = slot&1 (cols 0-3 / 4-6). acc[4co][4px].
// SKIP: also computes the 1x1 stride-2 downsample from the same staged tile.

template<int STRIDE, bool SKIP>
__global__ __launch_bounds__(256)
void conv_tile_k(const float* __restrict__ in, const float* __restrict__ wT,
                 const float* __restrict__ dw, const float* __restrict__ addend,
                 float* __restrict__ out, float* __restrict__ skipout,
                 int H, int W, int OH, int OW, int TX, int TY) {
    constexpr int IHT = 6 * STRIDE + 3;             // staged rows (halo incl)
    constexpr int IWT = 6 * STRIDE + 3;             // staged cols (halo incl)
    constexpr int IPITCH = (STRIDE == 1) ? 12 : 16;
    constexpr int RSPAN = 4 * STRIDE + 2;

    __shared__ float sin_[64 * IHT * IPITCH];
    __shared__ float wl[4 * WCHUNK];

    int b = blockIdx.x;
    int tx = b % TX; b /= TX;
    int ty = b % TY; int n = b / TY;
    int oy0 = ty * 7, ox0 = tx * 7;
    int iy0 = oy0 * STRIDE - 1, ix0 = ox0 * STRIDE - 1;

    const int t = threadIdx.x;
    const int wave = t >> 6, lane = t & 63;
    const int cb = t >> 4, cbl = cb & 3, slot = t & 15;
    const int row = slot >> 1, half = slot & 1;
    const int crow = (row < 7) ? row : 0;           // clamp idle slots
    const int co0 = cb * 4;
    float* wlw = wl + wave * WCHUNK;

    // ---- stage input tile (zero-padded) ----
    const float* ip = in + (size_t)n * 64 * H * W;
    for (int i = t; i < 64 * IHT * IPITCH; i += 256) {
        int c = i % IPITCH; int r = (i / IPITCH) % IHT; int ch = i / (IPITCH * IHT);
        int gy = iy0 + r, gx = ix0 + c;
        float v = 0.f;
        if (c < IWT && (unsigned)gy < (unsigned)H && (unsigned)gx < (unsigned)W)
            v = ip[(size_t)ch * H * W + gy * W + gx];
        sin_[i] = v;
    }
    __syncthreads();

    // ---- main 3x3 conv, streaming weights ----
    const float* wg = wT + (size_t)wave * WREGION;
    float acc[4][4];
#pragma unroll
    for (int j = 0; j < 4; j++)
#pragma unroll
        for (int px = 0; px < 4; px++) acc[j][px] = 0.f;

    float2 s0, s1, s2v;
    {
        const float2* gp = (const float2*)wg + lane * 3;
        s0 = gp[0]; s1 = gp[1]; s2v = gp[2];
    }
    for (int ch = 0; ch < 64 / KC; ch++) {
        {
            float2* wp = (float2*)wlw + lane * 3;
            wp[0] = s0; wp[1] = s1; wp[2] = s2v;
        }
        if (ch < 64 / KC - 1) {
            const float2* gp = (const float2*)(wg + (ch + 1) * WCHUNK) + lane * 3;
            s0 = gp[0]; s1 = gp[1]; s2v = gp[2];
        }
        float wr[KC][4][9];
#pragma unroll
        for (int c2 = 0; c2 < KC; c2++)
#pragma unroll
            for (int j = 0; j < 4; j++) {
                const float* wp2 = wlw + (c2 * 16 + cbl * 4 + j) * 12;
                float4 wa = *(const float4*)wp2;
                float4 wb = *(const float4*)(wp2 + 4);
                wr[c2][j][0] = wa.x; wr[c2][j][1] = wa.y; wr[c2][j][2] = wa.z;
                wr[c2][j][3] = wa.w; wr[c2][j][4] = wb.x; wr[c2][j][5] = wb.y;
                wr[c2][j][6] = wb.z; wr[c2][j][7] = wb.w; wr[c2][j][8] = wp2[8];
            }
#pragma unroll
        for (int c2 = 0; c2 < KC; c2++) {
            const float* hc = sin_ + ((ch * KC + c2) * IHT + crow * STRIDE) * IPITCH
                            + half * 4 * STRIDE;
            float rr[3][RSPAN];
#pragma unroll
            for (int ky = 0; ky < 3; ky++) {
                const float* bp = hc + ky * IPITCH;
                if constexpr (STRIDE == 1) {
                    float4 a = *(const float4*)bp; float2 bb = *(const float2*)(bp + 4);
                    rr[ky][0] = a.x; rr[ky][1] = a.y; rr[ky][2] = a.z; rr[ky][3] = a.w;
                    rr[ky][4] = bb.x; rr[ky][5] = bb.y;
                } else {
                    float4 a = *(const float4*)bp; float4 bb = *(const float4*)(bp + 4);
                    float2 cc = *(const float2*)(bp + 8);
                    rr[ky][0] = a.x; rr[ky][1] = a.y; rr[ky][2] = a.z; rr[ky][3] = a.w;
                    rr[ky][4] = bb.x; rr[ky][5] = bb.y; rr[ky][6] = bb.z; rr[ky][7] = bb.w;
                    rr[ky][8] = cc.x; rr[ky][9] = cc.y;
                }
            }
#pragma unroll
            for (int j = 0; j < 4; j++)
#pragma unroll
                for (int px = 0; px < 4; px++) {
                    float s = acc[j][px];
#pragma unroll
                    for (int ky = 0; ky < 3; ky++) {
                        s = fmaf(rr[ky][px * STRIDE + 0], wr[c2][j][ky * 3 + 0], s);
                        s = fmaf(rr[ky][px * STRIDE + 1], wr[c2][j][ky * 3 + 1], s);
                        s = fmaf(rr[ky][px * STRIDE + 2], wr[c2][j][ky * 3 + 2], s);
                    }
                    acc[j][px] = s;
                }
        }
    }

    // ---- optional fused 1x1 stride-2 skip conv from the same staged tile ----
    if constexpr (SKIP) {
        if (slot < 14) {
            float sk[4][4];
#pragma unroll
            for (int j = 0; j < 4; j++)
#pragma unroll
                for (int px = 0; px < 4; px++) sk[j][px] = 0.f;
            for (int ci = 0; ci < 64; ci++) {
                const float* sp = sin_ + (ci * IHT + 2 * row + 1) * IPITCH + half * 8 + 1;
                float xv[4];
#pragma unroll
                for (int px = 0; px < 4; px++) xv[px] = sp[px * 2];
#pragma unroll
                for (int j = 0; j < 4; j++) {
                    float wv = dw[(co0 + j) * 64 + ci];
#pragma unroll
                    for (int px = 0; px < 4; px++) sk[j][px] = fmaf(xv[px], wv, sk[j][px]);
                }
            }
#pragma unroll
            for (int j = 0; j < 4; j++)
#pragma unroll
                for (int px = 0; px < 4; px++) {
                    int oy = oy0 + row, ox = ox0 + half * 4 + px;
                    if (oy < OH && ox < OW && half * 4 + px < 7)
                        skipout[(((size_t)n * 64 + co0 + j) * OH + oy) * OW + ox] = sk[j][px];
                }
        }
    }

    // ---- epilogue ----
    if (slot < 14) {
#pragma unroll
        for (int j = 0; j < 4; j++)
#pragma unroll
            for (int px = 0; px < 4; px++) {
                int oy = oy0 + row, ox = ox0 + half * 4 + px;
                if (oy < OH && ox < OW && half * 4 + px < 7) {
                    size_t idx = (((size_t)n * 64 + co0 + j) * OH + oy) * OW + ox;
                    float v = acc[j][px];
                    if (addend) v += addend[idx];
                    out[idx] = v;
                }
            }
    }
}

// ======================= ODE mega-kernel =====================================

__global__ __launch_bounds__(256, 2)
void ode_mega_k(const float* __restrict__ z0g,
                const float* __restrict__ wT1, const float* __restrict__ wT2,
                const float* __restrict__ g1w, const float* __restrict__ g1b,
                const float* __restrict__ g2w, const float* __restrict__ g2b,
                const float* __restrict__ fgw, const float* __restrict__ fgb,
                const float* __restrict__ fcw, const float* __restrict__ fcb,
                float* __restrict__ out) {
    __shared__ float smem[4 * 3136 + 64 * H_CH + 4 * WCHUNK + 64];
    float* zb0 = smem;
    float* zb1 = smem + 3136;
    float* ub  = smem + 2 * 3136;
    float* h2  = smem + 3 * 3136;
    float* h   = smem + 4 * 3136;
    float* wl  = smem + 4 * 3136 + 64 * H_CH;
    float* pooled = wl + 4 * WCHUNK;

    const int t = threadIdx.x;
    const int n = blockIdx.x;
    const int c4 = t >> 2, q4 = t & 3;
    const int wave = t >> 6, lane = t & 63;
    const int cb = t >> 4, cbl = cb & 3, slot = t & 15;
    const int row = slot >> 1, half = slot & 1;
    const int co0 = cb * 4;
    float* wlw = wl + wave * WCHUNK;

    const float g1wv = g1w[c4], g1bv = g1b[c4];
    const float g2wv = g2w[c4], g2bv = g2b[c4];

    for (int i = t; i < 3136; i += 256) zb0[i] = z0g[(size_t)n * 3136 + i];
    for (int i = t; i < 64 * H_CH; i += 256) h[i] = 0.f;
    __syncthreads();

    auto gn64 = [&](const float* sp, float gwv, float gbv) {
        float v[13], s = 0.f, s2 = 0.f;
#pragma unroll
        for (int i = 0; i < 13; i++) {
            int p = q4 + i * 4;
            float x = (p < 49) ? sp[c4 * 49 + p] : 0.f;
            v[i] = x; s += x; s2 += x * x;
        }
        s += __shfl_xor(s, 1); s2 += __shfl_xor(s2, 1);
        s += __shfl_xor(s, 2); s2 += __shfl_xor(s2, 2);
        float m = s * (1.f / 49.f);
        float r = rsqrtf(s2 * (1.f / 49.f) - m * m + 1e-5f);
        float sc = r * gwv, sh = gbv - m * sc;
#pragma unroll
        for (int i = 0; i < 13; i++) {
            int p = q4 + i * 4;
            if (p < 49) {
                float y = fmaxf(v[i] * sc + sh, 0.f);
                h[(c4 * 7 + p / 7) * H_PITCH + (p % 7) + 1] = y;
            }
        }
    };

    auto convf = [&](const float* __restrict__ wT, int mode, int e, float ckv, float cuv,
                     const float* __restrict__ src, const float* __restrict__ zp,
                     float* __restrict__ znew) {
        const float* wg = wT + (size_t)wave * WREGION;
        float acc[4][4];
#pragma unroll
        for (int j = 0; j < 4; j++)
#pragma unroll
            for (int px = 0; px < 4; px++) acc[j][px] = 0.f;

        float2 s0, s1, s2v;
        {
            const float2* gp = (const float2*)wg + lane * 3;
            s0 = gp[0]; s1 = gp[1]; s2v = gp[2];
        }
        for (int ch = 0; ch < 64 / KC; ch++) {
            {
                float2* wp = (float2*)wlw + lane * 3;
                wp[0] = s0; wp[1] = s1; wp[2] = s2v;
            }
            if (ch < 64 / KC - 1) {
                const float2* gp = (const float2*)(wg + (ch + 1) * WCHUNK) + lane * 3;
                s0 = gp[0]; s1 = gp[1]; s2v = gp[2];
            }
            float wr[KC][4][9];
#pragma unroll
            for (int c2 = 0; c2 < KC; c2++)
#pragma unroll
                for (int j = 0; j < 4; j++) {
                    const float* wp2 = wlw + (c2 * 16 + cbl * 4 + j) * H_PITCH;
                    float4 wa = *(const float4*)wp2;
                    float4 wb = *(const float4*)(wp2 + 4);
                    wr[c2][j][0] = wa.x; wr[c2][j][1] = wa.y; wr[c2][j][2] = wa.z;
                    wr[c2][j][3] = wa.w; wr[c2][j][4] = wb.x; wr[c2][j][5] = wb.y;
                    wr[c2][j][6] = wb.z; wr[c2][j][7] = wb.w; wr[c2][j][8] = wp2[8];
                }
#pragma unroll
            for (int c2 = 0; c2 < KC; c2++) {
                const float* hc = h + (ch * KC + c2) * H_CH + half * 4;
                float r0[6], r1[6], r2[6];
                {
                    int ry = row - 1;
                    if ((unsigned)ry < 7u) {
                        float4 a = *(const float4*)(hc + ry * H_PITCH);
                        float2 b = *(const float2*)(hc + ry * H_PITCH + 4);
                        r0[0]=a.x; r0[1]=a.y; r0[2]=a.z; r0[3]=a.w; r0[4]=b.x; r0[5]=b.y;
                    } else { r0[0]=r0[1]=r0[2]=r0[3]=r0[4]=r0[5]=0.f; }
                }
                {
                    int ry = row;
                    if ((unsigned)ry < 7u) {
                        float4 a = *(const float4*)(hc + ry * H_PITCH);
                        float2 b = *(const float2*)(hc + ry * H_PITCH + 4);
                        r1[0]=a.x; r1[1]=a.y; r1[2]=a.z; r1[3]=a.w; r1[4]=b.x; r1[5]=b.y;
                    } else { r1[0]=r1[1]=r1[2]=r1[3]=r1[4]=r1[5]=0.f; }
                }
                {
                    int ry = row + 1;
                    if ((unsigned)ry < 7u) {
                        float4 a = *(const float4*)(hc + ry * H_PITCH);
                        float2 b = *(const float2*)(hc + ry * H_PITCH + 4);
                        r2[0]=a.x; r2[1]=a.y; r2[2]=a.z; r2[3]=a.w; r2[4]=b.x; r2[5]=b.y;
                    } else { r2[0]=r2[1]=r2[2]=r2[3]=r2[4]=r2[5]=0.f; }
                }
#pragma unroll
                for (int j = 0; j < 4; j++) {
#pragma unroll
                    for (int px = 0; px < 4; px++) {
                        float s = acc[j][px];
                        s = fmaf(r0[px + 0], wr[c2][j][0], s);
                        s = fmaf(r0[px + 1], wr[c2][j][1], s);
                        s = fmaf(r0[px + 2], wr[c2][j][2], s);
                        s = fmaf(r1[px + 0], wr[c2][j][3], s);
                        s = fmaf(r1[px + 1], wr[c2][j][4], s);
                        s = fmaf(r1[px + 2], wr[c2][j][5], s);
                        s = fmaf(r2[px + 0], wr[c2][j][6], s);
                        s = fmaf(r2[px + 1], wr[c2][j][7], s);
                        s = fmaf(r2[px + 2], wr[c2][j][8], s);
                        acc[j][px] = s;
                    }
                }
            }
        }
        if (slot < 14) {
#pragma unroll
            for (int j = 0; j < 4; j++)
#pragma unroll
                for (int px = 0; px < 4; px++) {
                    int col = half * 4 + px;
                    if (col < 7) {
                        int idx = (co0 + j) * 49 + row * 7 + col;
                        if (mode == 0) {
                            h2[idx] = acc[j][px];
                        } else {
                            float kv = acc[j][px] + src[idx];
                            float zi = zp[idx];
                            if (e == 0) znew[idx] = zi + ckv * kv;
                            else        znew[idx] += ckv * kv;
                            if (e < 3)  ub[idx] = zi + cuv * kv;
                        }
                    }
                }
        }
    };

    float* z = zb0; float* znew = zb1;
    const float dt = 0.5f;
    for (int step = 0; step < 12; step++) {
        for (int e = 0; e < 4; e++) {
            float ckv = (e == 0 || e == 3) ? dt / 6.f : dt / 3.f;
            float cuv = (e == 2) ? dt : dt * 0.5f;
            const float* src = (e == 0) ? z : ub;
            gn64(src, g1wv, g1bv);
            __syncthreads();
            convf(wT1, 0, 0, 0.f, 0.f, nullptr, nullptr, nullptr);
            __syncthreads();
            gn64(h2, g2wv, g2bv);
            __syncthreads();
            convf(wT2, 1, e, ckv, cuv, src, z, znew);
            __syncthreads();
        }
        float* tmp = z; z = znew; znew = tmp;
    }

    {
        float v[13], s = 0.f, s2 = 0.f;
#pragma unroll
        for (int i = 0; i < 13; i++) {
            int p = q4 + i * 4;
            float x = (p < 49) ? z[c4 * 49 + p] : 0.f;
            v[i] = x; s += x; s2 += x * x;
        }
        s += __shfl_xor(s, 1); s2 += __shfl_xor(s2, 1);
        s += __shfl_xor(s, 2); s2 += __shfl_xor(s2, 2);
        s += __shfl_xor(s, 4); s2 += __shfl_xor(s2, 4);
        float m = s * (1.f / 98.f);
        float r = rsqrtf(s2 * (1.f / 98.f) - m * m + 1e-5f);
        float sc = r * fgw[c4], sh = fgb[c4] - m * sc;
        float ps = 0.f;
#pragma unroll
        for (int i = 0; i < 13; i++) {
            int p = q4 + i * 4;
            if (p < 49) ps += fmaxf(v[i] * sc + sh, 0.f);
        }
        ps += __shfl_xor(ps, 1);
        ps += __shfl_xor(ps, 2);
        if (q4 == 0) pooled[c4] = ps * (1.f / 49.f);
    }
    __syncthreads();
    if (t < 10) {
        float a = fcb[t];
#pragma unroll
        for (int k = 0; k < 64; k++) a += pooled[k] * fcw[t * 64 + k];
        out[(size_t)n * 10 + t] = a;
    }
}

static inline int nblk(long long total) { return (int)((total + TPB - 1) / TPB); }

extern "C" void kernel_launch(void* const* d_in, const int* in_sizes, int n_in,
                              void* d_out, int out_size, void* d_ws, size_t ws_size,
                              hipStream_t stream) {
    const float* x       = (const float*)d_in[0];
    const float* conv1_w = (const float*)d_in[1];
    const float* conv1_b = (const float*)d_in[2];
    const float* r1_g1w  = (const float*)d_in[3];
    const float* r1_g1b  = (const float*)d_in[4];
    const float* r1_c1w  = (const float*)d_in[5];
    const float* r1_g2w  = (const float*)d_in[6];
    const float* r1_g2b  = (const float*)d_in[7];
    const float* r1_c2w  = (const float*)d_in[8];
    const float* r1_dw   = (const float*)d_in[9];
    const float* r2_g1w  = (const float*)d_in[10];
    const float* r2_g1b  = (const float*)d_in[11];
    const float* r2_c1w  = (const float*)d_in[12];
    const float* r2_g2w  = (const float*)d_in[13];
    const float* r2_g2b  = (const float*)d_in[14];
    const float* r2_c2w  = (const float*)d_in[15];
    const float* r2_dw   = (const float*)d_in[16];
    const float* o_g1w   = (const float*)d_in[17];
    const float* o_g1b   = (const float*)d_in[18];
    const float* o_c1w   = (const float*)d_in[19];
    const float* o_g2w   = (const float*)d_in[20];
    const float* o_g2b   = (const float*)d_in[21];
    const float* o_c2w   = (const float*)d_in[22];
    const float* fin_gw  = (const float*)d_in[23];
    const float* fin_gb  = (const float*)d_in[24];
    const float* fc_w    = (const float*)d_in[25];
    const float* fc_b    = (const float*)d_in[26];
    float* out = (float*)d_out;

    const int N = 512;
    const long long SZ26 = 512LL * 64 * 26 * 26;
    const long long SZ13 = 512LL * 64 * 13 * 13;
    const long long SZ7  = 512LL * 64 * 7 * 7;
    const long long WTS  = 64 * 64 * 12;

    float* B26  = (float*)d_ws;
    float* A13  = B26 + SZ26;
    float* B13  = A13 + SZ13;
    float* Z7   = B13 + SZ13;
    float* U7   = Z7 + SZ7;
    float* MEAN = U7 + SZ7;
    float* RSTD = MEAN + 512 * 64;
    float* WTo1 = RSTD + 512 * 64;
    float* WTo2 = WTo1 + WTS;
    float* WTr11 = WTo2 + WTS;
    float* WTr12 = WTr11 + WTS;
    float* WTr21 = WTr12 + WTS;
    float* WTr22 = WTr21 + WTS;

    auto gn = [&](const float* src, float* dst, int HW, int G,
                  const float* gw, const float* gb) {
        int waves = N * G;
        gn_stats_k<<<nblk((long long)waves * 64), TPB, 0, stream>>>(src, MEAN, RSTD, N, 64, HW, G);
        gn_apply_relu_k<<<nblk((long long)N * 64 * HW), TPB, 0, stream>>>(
            src, dst, MEAN, RSTD, gw, gb, N, 64, HW, G);
    };

    // ---- weight prep ----
    wprep_k<<<nblk(WTS), TPB, 0, stream>>>(o_c1w, WTo1);
    wprep_k<<<nblk(WTS), TPB, 0, stream>>>(o_c2w, WTo2);
    wprep_k<<<nblk(WTS), TPB, 0, stream>>>(r1_c1w, WTr11);
    wprep_k<<<nblk(WTS), TPB, 0, stream>>>(r1_c2w, WTr12);
    wprep_k<<<nblk(WTS), TPB, 0, stream>>>(r2_c1w, WTr21);
    wprep_k<<<nblk(WTS), TPB, 0, stream>>>(r2_c2w, WTr22);

    // ---- stage 0: conv1 ----
    conv1_k<<<nblk(SZ26), TPB, 0, stream>>>(x, conv1_w, conv1_b, B26);

    // ---- residual block 1: 26x26 -> 13x13 ----
    gn(B26, B26, 676, 32, r1_g1w, r1_g1b);
    conv_tile_k<2, true><<<512 * 4, 256, 0, stream>>>(B26, WTr11, r1_dw, nullptr,
                                                      A13, B13, 26, 26, 13, 13, 2, 2);
    gn(A13, A13, 169, 32, r1_g2w, r1_g2b);
    conv_tile_k<1, false><<<512 * 4, 256, 0, stream>>>(A13, WTr12, nullptr, B13,
                                                       B13, nullptr, 13, 13, 13, 13, 2, 2);

    // ---- residual block 2: 13x13 -> 7x7 ----
    gn(B13, B13, 169, 32, r2_g1w, r2_g1b);
    conv_tile_k<2, true><<<512, 256, 0, stream>>>(B13, WTr21, r2_dw, nullptr,
                                                  U7, Z7, 13, 13, 7, 7, 1, 1);
    gn(U7, U7, 49, 32, r2_g2w, r2_g2b);
    conv_tile_k<1, false><<<512, 256, 0, stream>>>(U7, WTr22, nullptr, Z7,
                                                   Z7, nullptr, 7, 7, 7, 7, 1, 1);

    // ---- fused ODE (12 RK4 steps) + final GN + pool + FC ----
    ode_mega_k<<<512, 256, 0, stream>>>(Z7, WTo1, WTo2,
                                        o_g1w, o_g1b, o_g2w, o_g2b,
                                        fin_gw, fin_gb, fc_w, fc_b, out);
}

// Round 5
// 2727.605 us; speedup vs baseline: 17.1486x; 1.7388x over previous
//
#include <hip/hip_runtime.h>
#include <hip/hip_bf16.h>

#define TPB 256

typedef __attribute__((ext_vector_type(8))) short short8;
typedef __attribute__((ext_vector_type(4))) float f32x4;

__device__ __forceinline__ unsigned short f2bf(float x) {
    union { float f; unsigned int u; } c; c.f = x;
    unsigned int u = c.u;
    unsigned int r = (u + 0x7fffu + ((u >> 16) & 1u)) >> 16;
    return (unsigned short)r;
}
__device__ __forceinline__ float bf2f(unsigned short h) {
    union { unsigned int u; float f; } c; c.u = ((unsigned int)h) << 16;
    return c.f;
}

// ======================= small prologue kernels ==============================

__global__ void conv1_k(const float* __restrict__ x, const float* __restrict__ w,
                        const float* __restrict__ b, float* __restrict__ out) {
    int idx = blockIdx.x * TPB + threadIdx.x;
    const int total = 512 * 64 * 26 * 26;
    if (idx >= total) return;
    int ox = idx % 26; int t = idx / 26;
    int oy = t % 26;   t /= 26;
    int co = t % 64;   int n = t / 64;
    const float* xp = x + (size_t)n * 784 + oy * 28 + ox;
    const float* wp = w + co * 9;
    float s = b[co];
#pragma unroll
    for (int ky = 0; ky < 3; ky++)
#pragma unroll
        for (int kx = 0; kx < 3; kx++)
            s += xp[ky * 28 + kx] * wp[ky * 3 + kx];
    out[idx] = s;
}

__global__ void gn_stats_k(const float* __restrict__ x, float* __restrict__ mean,
                           float* __restrict__ rstd, int N, int C, int HW, int G) {
    int gid  = (blockIdx.x * blockDim.x + threadIdx.x) >> 6;
    int lane = threadIdx.x & 63;
    int total = N * G;
    if (gid >= total) return;
    int n = gid / G, g = gid % G;
    int cpg = C / G;
    int gsize = cpg * HW;
    const float* p = x + ((size_t)n * C + (size_t)g * cpg) * HW;
    float s = 0.f, s2 = 0.f;
    for (int i = lane; i < gsize; i += 64) { float v = p[i]; s += v; s2 += v * v; }
#pragma unroll
    for (int off = 32; off; off >>= 1) {
        s  += __shfl_down(s,  off);
        s2 += __shfl_down(s2, off);
    }
    if (lane == 0) {
        float m = s / gsize;
        float var = s2 / gsize - m * m;
        mean[gid] = m;
        rstd[gid] = rsqrtf(var + 1e-5f);
    }
}

__global__ void gn_apply_relu_k(const float* __restrict__ x, float* __restrict__ out,
                                const float* __restrict__ mean, const float* __restrict__ rstd,
                                const float* __restrict__ gw, const float* __restrict__ gb,
                                int N, int C, int HW, int G) {
    int idx = blockIdx.x * TPB + threadIdx.x;
    int total = N * C * HW;
    if (idx >= total) return;
    int c = (idx / HW) % C;
    int n = idx / (HW * C);
    int cpg = C / G;
    int g = c / cpg;
    float m = mean[n * G + g], r = rstd[n * G + g];
    float v = (x[idx] - m) * r * gw[c] + gb[c];
    out[idx] = v > 0.f ? v : 0.f;
}

// prologue weight transpose: w[co][ci][3][3] -> wT[wave][ci][col16][12]
__global__ void wprep_k(const float* __restrict__ w, float* __restrict__ wT) {
    int i = blockIdx.x * TPB + threadIdx.x;
    if (i >= 64 * 64 * 12) return;
    int k = i % 12; int r = i / 12;
    int col = r % 16; r /= 16;
    int ci = r % 64; int wave = r / 64;
    int co = wave * 16 + col;
    wT[i] = (k < 9) ? w[(co * 64 + ci) * 9 + k] : 0.f;
}

// ODE weight split: w[co][ci][3][3] -> hi/lo bf16 B-frag tables
// layout [t:9][ks:2][nt:4][lane:64][8]: lane holds B[k=ks*32+(l>>4)*8+j][co=nt*16+(l&15)]
__global__ void wsplit_k(const float* __restrict__ w, unsigned short* __restrict__ hiT,
                         unsigned short* __restrict__ loT) {
    int i = blockIdx.x * TPB + threadIdx.x;
    if (i >= 9 * 2 * 4 * 64 * 8) return;
    int j = i & 7, l = (i >> 3) & 63, nt = (i >> 9) & 3, ks = (i >> 11) & 1, t = i >> 12;
    int co = nt * 16 + (l & 15);
    int ci = ks * 32 + (l >> 4) * 8 + j;
    float wv = w[(co * 64 + ci) * 9 + t];
    unsigned short hi = f2bf(wv);
    hiT[i] = hi;
    loT[i] = f2bf(wv - bf2f(hi));
}

// ======================= tiled 3x3 conv (prologue) ===========================

#define KC 2
#define WCHUNK (KC * 16 * 12)
#define WREGION (64 * 16 * 12)

template<int STRIDE, bool SKIP>
__global__ __launch_bounds__(256)
void conv_tile_k(const float* __restrict__ in, const float* __restrict__ wT,
                 const float* __restrict__ dw, const float* __restrict__ addend,
                 float* __restrict__ out, float* __restrict__ skipout,
                 int H, int W, int OH, int OW, int TX, int TY) {
    constexpr int IHT = 6 * STRIDE + 3;
    constexpr int IWT = 6 * STRIDE + 3;
    constexpr int IPITCH = (STRIDE == 1) ? 12 : 16;
    constexpr int RSPAN = 4 * STRIDE + 2;

    __shared__ float sin_[64 * IHT * IPITCH];
    __shared__ float wl[4 * WCHUNK];

    int b = blockIdx.x;
    int tx = b % TX; b /= TX;
    int ty = b % TY; int n = b / TY;
    int oy0 = ty * 7, ox0 = tx * 7;
    int iy0 = oy0 * STRIDE - 1, ix0 = ox0 * STRIDE - 1;

    const int t = threadIdx.x;
    const int wave = t >> 6, lane = t & 63;
    const int cb = t >> 4, cbl = cb & 3, slot = t & 15;
    const int row = slot >> 1, half = slot & 1;
    const int crow = (row < 7) ? row : 0;
    const int co0 = cb * 4;
    float* wlw = wl + wave * WCHUNK;

    const float* ip = in + (size_t)n * 64 * H * W;
    for (int i = t; i < 64 * IHT * IPITCH; i += 256) {
        int c = i % IPITCH; int r = (i / IPITCH) % IHT; int ch = i / (IPITCH * IHT);
        int gy = iy0 + r, gx = ix0 + c;
        float v = 0.f;
        if (c < IWT && (unsigned)gy < (unsigned)H && (unsigned)gx < (unsigned)W)
            v = ip[(size_t)ch * H * W + gy * W + gx];
        sin_[i] = v;
    }
    __syncthreads();

    const float* wg = wT + (size_t)wave * WREGION;
    float acc[4][4];
#pragma unroll
    for (int j = 0; j < 4; j++)
#pragma unroll
        for (int px = 0; px < 4; px++) acc[j][px] = 0.f;

    float2 s0, s1, s2v;
    {
        const float2* gp = (const float2*)wg + lane * 3;
        s0 = gp[0]; s1 = gp[1]; s2v = gp[2];
    }
    for (int ch = 0; ch < 64 / KC; ch++) {
        {
            float2* wp = (float2*)wlw + lane * 3;
            wp[0] = s0; wp[1] = s1; wp[2] = s2v;
        }
        if (ch < 64 / KC - 1) {
            const float2* gp = (const float2*)(wg + (ch + 1) * WCHUNK) + lane * 3;
            s0 = gp[0]; s1 = gp[1]; s2v = gp[2];
        }
        float wr[KC][4][9];
#pragma unroll
        for (int c2 = 0; c2 < KC; c2++)
#pragma unroll
            for (int j = 0; j < 4; j++) {
                const float* wp2 = wlw + (c2 * 16 + cbl * 4 + j) * 12;
                float4 wa = *(const float4*)wp2;
                float4 wb = *(const float4*)(wp2 + 4);
                wr[c2][j][0] = wa.x; wr[c2][j][1] = wa.y; wr[c2][j][2] = wa.z;
                wr[c2][j][3] = wa.w; wr[c2][j][4] = wb.x; wr[c2][j][5] = wb.y;
                wr[c2][j][6] = wb.z; wr[c2][j][7] = wb.w; wr[c2][j][8] = wp2[8];
            }
#pragma unroll
        for (int c2 = 0; c2 < KC; c2++) {
            const float* hc = sin_ + ((ch * KC + c2) * IHT + crow * STRIDE) * IPITCH
                            + half * 4 * STRIDE;
            float rr[3][RSPAN];
#pragma unroll
            for (int ky = 0; ky < 3; ky++) {
                const float* bp = hc + ky * IPITCH;
                if constexpr (STRIDE == 1) {
                    float4 a = *(const float4*)bp; float2 bb = *(const float2*)(bp + 4);
                    rr[ky][0] = a.x; rr[ky][1] = a.y; rr[ky][2] = a.z; rr[ky][3] = a.w;
                    rr[ky][4] = bb.x; rr[ky][5] = bb.y;
                } else {
                    float4 a = *(const float4*)bp; float4 bb = *(const float4*)(bp + 4);
                    float2 cc = *(const float2*)(bp + 8);
                    rr[ky][0] = a.x; rr[ky][1] = a.y; rr[ky][2] = a.z; rr[ky][3] = a.w;
                    rr[ky][4] = bb.x; rr[ky][5] = bb.y; rr[ky][6] = bb.z; rr[ky][7] = bb.w;
                    rr[ky][8] = cc.x; rr[ky][9] = cc.y;
                }
            }
#pragma unroll
            for (int j = 0; j < 4; j++)
#pragma unroll
                for (int px = 0; px < 4; px++) {
                    float s = acc[j][px];
#pragma unroll
                    for (int ky = 0; ky < 3; ky++) {
                        s = fmaf(rr[ky][px * STRIDE + 0], wr[c2][j][ky * 3 + 0], s);
                        s = fmaf(rr[ky][px * STRIDE + 1], wr[c2][j][ky * 3 + 1], s);
                        s = fmaf(rr[ky][px * STRIDE + 2], wr[c2][j][ky * 3 + 2], s);
                    }
                    acc[j][px] = s;
                }
        }
    }

    if constexpr (SKIP) {
        if (slot < 14) {
            float sk[4][4];
#pragma unroll
            for (int j = 0; j < 4; j++)
#pragma unroll
                for (int px = 0; px < 4; px++) sk[j][px] = 0.f;
            for (int ci = 0; ci < 64; ci++) {
                const float* sp = sin_ + (ci * IHT + 2 * row + 1) * IPITCH + half * 8 + 1;
                float xv[4];
#pragma unroll
                for (int px = 0; px < 4; px++) xv[px] = sp[px * 2];
#pragma unroll
                for (int j = 0; j < 4; j++) {
                    float wv = dw[(co0 + j) * 64 + ci];
#pragma unroll
                    for (int px = 0; px < 4; px++) sk[j][px] = fmaf(xv[px], wv, sk[j][px]);
                }
            }
#pragma unroll
            for (int j = 0; j < 4; j++)
#pragma unroll
                for (int px = 0; px < 4; px++) {
                    int oy = oy0 + row, ox = ox0 + half * 4 + px;
                    if (oy < OH && ox < OW && half * 4 + px < 7)
                        skipout[(((size_t)n * 64 + co0 + j) * OH + oy) * OW + ox] = sk[j][px];
                }
        }
    }

    if (slot < 14) {
#pragma unroll
        for (int j = 0; j < 4; j++)
#pragma unroll
            for (int px = 0; px < 4; px++) {
                int oy = oy0 + row, ox = ox0 + half * 4 + px;
                if (oy < OH && ox < OW && half * 4 + px < 7) {
                    size_t idx = (((size_t)n * 64 + co0 + j) * OH + oy) * OW + ox;
                    float v = acc[j][px];
                    if (addend) v += addend[idx];
                    out[idx] = v;
                }
            }
    }
}

// ======================= ODE MFMA mega-kernel ================================
// Block = one image, 4 waves; wave owns one 16-co N-tile. Conv = 9 tap-GEMMs
// (M=49->4x16, K=64, N=64) with mfma_f32_16x16x32_bf16. Activations: bf16 in
// halo-padded LDS plane (9x9 pixel slots x 64ch, pitch 72). Weights: hi/lo
// bf16 fragments streamed from L2. z/u/k state: fp32 LDS, pitch 52.
// GN2 fully in-register.
//
// Halo addressing: pixel p's center slot hb = (p/7+1)*9 + (p%7)+1; tap
// (ky,kx) reads slot hb + (ky-1)*9 + (kx-1)  [the -10 matters!].

#define HP_PITCH 72          // ushorts per pixel-slot (144 B)
#define ZP 52                // fp32 state pitch per channel

__global__ __launch_bounds__(256, 2)
void ode_mfma_k(const float* __restrict__ z0g,
                const unsigned short* __restrict__ wb1h, const unsigned short* __restrict__ wb1l,
                const unsigned short* __restrict__ wb2h, const unsigned short* __restrict__ wb2l,
                const float* __restrict__ g1w, const float* __restrict__ g1b,
                const float* __restrict__ g2w, const float* __restrict__ g2b,
                const float* __restrict__ fgw, const float* __restrict__ fgb,
                const float* __restrict__ fcw, const float* __restrict__ fcb,
                float* __restrict__ out) {
    __shared__ float zA[64 * ZP], zB[64 * ZP], ubuf[64 * ZP];
    __shared__ unsigned short hp1[82 * HP_PITCH], hp2[82 * HP_PITCH];
    __shared__ float pooled[64];

    const int t = threadIdx.x;
    const int n = blockIdx.x;
    const int lane = t & 63;
    const int nt = t >> 6;                 // wave = N-tile
    const int colL = lane & 15, q = lane >> 4;
    const int co = nt * 16 + colL;
    const int c4 = t >> 2, q4 = t & 3;     // GN1 map

    const float g1wv = g1w[c4], g1bv = g1b[c4];
    const float g2wv = g2w[co], g2bv = g2b[co];

    // per-lane A-row bases (center slot per m-tile; 1000 = invalid sentinel)
    int hb[4];
#pragma unroll
    for (int m = 0; m < 4; m++) {
        int p = m * 16 + colL;
        hb[m] = (p < 49) ? ((p / 7 + 1) * 9 + (p % 7) + 1) : 1000;
    }
    const int kq0 = q * 8;

    // ---- init ----
    for (int i = t; i < 64 * ZP; i += 256) { zA[i] = 0.f; zB[i] = 0.f; ubuf[i] = 0.f; }
    for (int i = t; i < 82 * HP_PITCH; i += 256) { hp1[i] = 0; hp2[i] = 0; }
    __syncthreads();
    for (int i = t; i < 3136; i += 256) {
        int c = i / 49, p = i % 49;
        zA[c * ZP + p] = z0g[(size_t)n * 3136 + i];
    }
    __syncthreads();

    // conv via tap-GEMMs: A from hp, B(hi/lo) from global tables
    auto conv_mfma = [&](const unsigned short* __restrict__ hp,
                         const unsigned short* __restrict__ bhT,
                         const unsigned short* __restrict__ blT,
                         f32x4 acc[4]) {
        const short8* bh = (const short8*)bhT;
        const short8* bl = (const short8*)blT;
#pragma unroll
        for (int t9 = 0; t9 < 9; t9++) {
            const int toff = (t9 / 3) * 9 + (t9 % 3) - 10;   // (ky-1)*9 + (kx-1)
#pragma unroll
            for (int ks = 0; ks < 2; ks++) {
                int fidx = ((t9 * 2 + ks) * 4 + nt) * 64 + lane;
                short8 vbh = bh[fidx];
                short8 vbl = bl[fidx];
                int kq = ks * 32 + kq0;
#pragma unroll
                for (int m = 0; m < 4; m++) {
                    int hrow = min(hb[m] + toff, 81);
                    int idx = hrow * HP_PITCH + kq;
                    short8 a = *(const short8*)(hp + idx);
                    acc[m] = __builtin_amdgcn_mfma_f32_16x16x32_bf16(a, vbh, acc[m], 0, 0, 0);
                    acc[m] = __builtin_amdgcn_mfma_f32_16x16x32_bf16(a, vbl, acc[m], 0, 0, 0);
                }
            }
        }
    };

    float* z  = zA;
    float* zn = zB;
    const float dt = 0.5f;

#pragma unroll 1
    for (int step = 0; step < 12; step++) {
#pragma unroll 1
        for (int e = 0; e < 4; e++) {
            const float ck = (e == 0 || e == 3) ? dt / 6.f : dt / 3.f;
            const float cu = (e == 2) ? dt : 0.5f * dt;
            const float* src = (e == 0) ? z : ubuf;

            // ---- GN1(groups=64)+ReLU: src -> hp1 (bf16, halo layout) ----
            {
                float v[13], s = 0.f, s2 = 0.f;
#pragma unroll
                for (int i = 0; i < 13; i++) {
                    int p = q4 + i * 4;
                    float x = (p < 49) ? src[c4 * ZP + p] : 0.f;
                    v[i] = x; s += x; s2 += x * x;
                }
                s += __shfl_xor(s, 1); s2 += __shfl_xor(s2, 1);
                s += __shfl_xor(s, 2); s2 += __shfl_xor(s2, 2);
                float mu = s * (1.f / 49.f);
                float r = rsqrtf(s2 * (1.f / 49.f) - mu * mu + 1e-5f);
                float sc = r * g1wv, sh = g1bv - mu * sc;
#pragma unroll
                for (int i = 0; i < 13; i++) {
                    int p = q4 + i * 4;
                    if (p < 49) {
                        float y = fmaxf(v[i] * sc + sh, 0.f);
                        int hr = (p / 7 + 1) * 9 + (p % 7) + 1;
                        hp1[hr * HP_PITCH + c4] = f2bf(y);
                    }
                }
            }
            __syncthreads();

            // ---- conv1 + in-register GN2(groups=64)+ReLU -> hp2 ----
            {
                f32x4 acc[4];
#pragma unroll
                for (int m = 0; m < 4; m++) acc[m] = (f32x4){0.f, 0.f, 0.f, 0.f};
                conv_mfma(hp1, wb1h, wb1l, acc);

                float s = 0.f, s2 = 0.f;
#pragma unroll
                for (int m = 0; m < 4; m++)
#pragma unroll
                    for (int j = 0; j < 4; j++) {
                        int p = m * 16 + q * 4 + j;
                        if (p < 49) { float x = acc[m][j]; s += x; s2 += x * x; }
                    }
                s += __shfl_xor(s, 16); s2 += __shfl_xor(s2, 16);
                s += __shfl_xor(s, 32); s2 += __shfl_xor(s2, 32);
                float mu = s * (1.f / 49.f);
                float r = rsqrtf(s2 * (1.f / 49.f) - mu * mu + 1e-5f);
                float sc = r * g2wv, sh = g2bv - mu * sc;
#pragma unroll
                for (int m = 0; m < 4; m++)
#pragma unroll
                    for (int j = 0; j < 4; j++) {
                        int p = m * 16 + q * 4 + j;
                        if (p < 49) {
                            float y = fmaxf(acc[m][j] * sc + sh, 0.f);
                            int hr = (p / 7 + 1) * 9 + (p % 7) + 1;
                            hp2[hr * HP_PITCH + co] = f2bf(y);
                        }
                    }
            }
            __syncthreads();

            // ---- conv2 + RK4 epilogue ----
            {
                f32x4 acc[4];
#pragma unroll
                for (int m = 0; m < 4; m++) acc[m] = (f32x4){0.f, 0.f, 0.f, 0.f};
                conv_mfma(hp2, wb2h, wb2l, acc);

                const int rowb = co * ZP;
#pragma unroll
                for (int m = 0; m < 4; m++) {
                    int pb = m * 16 + q * 4;
                    if (pb < 49) {
                        f32x4 sv = *(const f32x4*)(src + rowb + pb);
                        f32x4 zv = (e == 0) ? sv : *(const f32x4*)(z + rowb + pb);
                        f32x4 kv;
#pragma unroll
                        for (int j = 0; j < 4; j++) kv[j] = acc[m][j] + sv[j];
                        f32x4 zo = (e == 0) ? zv : *(const f32x4*)(zn + rowb + pb);
#pragma unroll
                        for (int j = 0; j < 4; j++) zo[j] += ck * kv[j];
                        *(f32x4*)(zn + rowb + pb) = zo;
                        if (e < 3) {
                            f32x4 uo;
#pragma unroll
                            for (int j = 0; j < 4; j++) uo[j] = zv[j] + cu * kv[j];
                            *(f32x4*)(ubuf + rowb + pb) = uo;
                        }
                    }
                }
            }
            __syncthreads();
        }
        float* tmp = z; z = zn; zn = tmp;
    }

    // ---- final GN(groups=32)+ReLU + mean-pool ----
    {
        float v[13], s = 0.f, s2 = 0.f;
#pragma unroll
        for (int i = 0; i < 13; i++) {
            int p = q4 + i * 4;
            float x = (p < 49) ? z[c4 * ZP + p] : 0.f;
            v[i] = x; s += x; s2 += x * x;
        }
        s += __shfl_xor(s, 1); s2 += __shfl_xor(s2, 1);
        s += __shfl_xor(s, 2); s2 += __shfl_xor(s2, 2);
        s += __shfl_xor(s, 4); s2 += __shfl_xor(s2, 4);   // pair channels (G=32)
        float mu = s * (1.f / 98.f);
        float r = rsqrtf(s2 * (1.f / 98.f) - mu * mu + 1e-5f);
        float sc = r * fgw[c4], sh = fgb[c4] - mu * sc;
        float ps = 0.f;
#pragma unroll
        for (int i = 0; i < 13; i++) {
            int p = q4 + i * 4;
            if (p < 49) ps += fmaxf(v[i] * sc + sh, 0.f);
        }
        ps += __shfl_xor(ps, 1);
        ps += __shfl_xor(ps, 2);
        if (q4 == 0) pooled[c4] = ps * (1.f / 49.f);
    }
    __syncthreads();
    if (t < 10) {
        float a = fcb[t];
#pragma unroll
        for (int k = 0; k < 64; k++) a += pooled[k] * fcw[t * 64 + k];
        out[(size_t)n * 10 + t] = a;
    }
}

static inline int nblk(long long total) { return (int)((total + TPB - 1) / TPB); }

extern "C" void kernel_launch(void* const* d_in, const int* in_sizes, int n_in,
                              void* d_out, int out_size, void* d_ws, size_t ws_size,
                              hipStream_t stream) {
    const float* x       = (const float*)d_in[0];
    const float* conv1_w = (const float*)d_in[1];
    const float* conv1_b = (const float*)d_in[2];
    const float* r1_g1w  = (const float*)d_in[3];
    const float* r1_g1b  = (const float*)d_in[4];
    const float* r1_c1w  = (const float*)d_in[5];
    const float* r1_g2w  = (const float*)d_in[6];
    const float* r1_g2b  = (const float*)d_in[7];
    const float* r1_c2w  = (const float*)d_in[8];
    const float* r1_dw   = (const float*)d_in[9];
    const float* r2_g1w  = (const float*)d_in[10];
    const float* r2_g1b  = (const float*)d_in[11];
    const float* r2_c1w  = (const float*)d_in[12];
    const float* r2_g2w  = (const float*)d_in[13];
    const float* r2_g2b  = (const float*)d_in[14];
    const float* r2_c2w  = (const float*)d_in[15];
    const float* r2_dw   = (const float*)d_in[16];
    const float* o_g1w   = (const float*)d_in[17];
    const float* o_g1b   = (const float*)d_in[18];
    const float* o_c1w   = (const float*)d_in[19];
    const float* o_g2w   = (const float*)d_in[20];
    const float* o_g2b   = (const float*)d_in[21];
    const float* o_c2w   = (const float*)d_in[22];
    const float* fin_gw  = (const float*)d_in[23];
    const float* fin_gb  = (const float*)d_in[24];
    const float* fc_w    = (const float*)d_in[25];
    const float* fc_b    = (const float*)d_in[26];
    float* out = (float*)d_out;

    const int N = 512;
    const long long SZ26 = 512LL * 64 * 26 * 26;
    const long long SZ13 = 512LL * 64 * 13 * 13;
    const long long SZ7  = 512LL * 64 * 7 * 7;
    const long long WTS  = 64 * 64 * 12;
    const long long WBS  = 9 * 2 * 4 * 64 * 8;     // 36864 ushorts per table

    float* B26   = (float*)d_ws;
    float* A13   = B26 + SZ26;
    float* B13   = A13 + SZ13;
    float* Z7    = B13 + SZ13;
    float* U7    = Z7 + SZ7;
    float* MEAN  = U7 + SZ7;
    float* RSTD  = MEAN + 512 * 64;
    float* WTr11 = RSTD + 512 * 64;
    float* WTr12 = WTr11 + WTS;
    float* WTr21 = WTr12 + WTS;
    float* WTr22 = WTr21 + WTS;
    unsigned short* WB1h = (unsigned short*)(WTr22 + WTS);
    unsigned short* WB1l = WB1h + WBS;
    unsigned short* WB2h = WB1l + WBS;
    unsigned short* WB2l = WB2h + WBS;

    auto gn = [&](const float* src, float* dst, int HW, int G,
                  const float* gw, const float* gb) {
        int waves = N * G;
        gn_stats_k<<<nblk((long long)waves * 64), TPB, 0, stream>>>(src, MEAN, RSTD, N, 64, HW, G);
        gn_apply_relu_k<<<nblk((long long)N * 64 * HW), TPB, 0, stream>>>(
            src, dst, MEAN, RSTD, gw, gb, N, 64, HW, G);
    };

    // ---- weight prep ----
    wprep_k<<<nblk(WTS), TPB, 0, stream>>>(r1_c1w, WTr11);
    wprep_k<<<nblk(WTS), TPB, 0, stream>>>(r1_c2w, WTr12);
    wprep_k<<<nblk(WTS), TPB, 0, stream>>>(r2_c1w, WTr21);
    wprep_k<<<nblk(WTS), TPB, 0, stream>>>(r2_c2w, WTr22);
    wsplit_k<<<nblk(WBS), TPB, 0, stream>>>(o_c1w, WB1h, WB1l);
    wsplit_k<<<nblk(WBS), TPB, 0, stream>>>(o_c2w, WB2h, WB2l);

    // ---- stage 0: conv1 ----
    conv1_k<<<nblk(SZ26), TPB, 0, stream>>>(x, conv1_w, conv1_b, B26);

    // ---- residual block 1: 26x26 -> 13x13 ----
    gn(B26, B26, 676, 32, r1_g1w, r1_g1b);
    conv_tile_k<2, true><<<512 * 4, 256, 0, stream>>>(B26, WTr11, r1_dw, nullptr,
                                                      A13, B13, 26, 26, 13, 13, 2, 2);
    gn(A13, A13, 169, 32, r1_g2w, r1_g2b);
    conv_tile_k<1, false><<<512 * 4, 256, 0, stream>>>(A13, WTr12, nullptr, B13,
                                                       B13, nullptr, 13, 13, 13, 13, 2, 2);

    // ---- residual block 2: 13x13 -> 7x7 ----
    gn(B13, B13, 169, 32, r2_g1w, r2_g1b);
    conv_tile_k<2, true><<<512, 256, 0, stream>>>(B13, WTr21, r2_dw, nullptr,
                                                  U7, Z7, 13, 13, 7, 7, 1, 1);
    gn(U7, U7, 49, 32, r2_g2w, r2_g2b);
    conv_tile_k<1, false><<<512, 256, 0, stream>>>(U7, WTr22, nullptr, Z7,
                                                   Z7, nullptr, 7, 7, 7, 7, 1, 1);

    // ---- fused MFMA ODE (12 RK4 steps) + final GN + pool + FC ----
    ode_mfma_k<<<512, 256, 0, stream>>>(Z7, WB1h, WB1l, WB2h, WB2l,
                                        o_g1w, o_g1b, o_g2w, o_g2b,
                                        fin_gw, fin_gb, fc_w, fc_b, out);
}

// Round 7
// 2041.828 us; speedup vs baseline: 22.9082x; 1.3359x over previous
//
#include <hip/hip_runtime.h>
#include <hip/hip_bf16.h>

#define TPB 256

typedef __attribute__((ext_vector_type(8))) short short8;
typedef __attribute__((ext_vector_type(4))) float f32x4;

__device__ __forceinline__ unsigned short f2bf(float x) {
    union { float f; unsigned int u; } c; c.f = x;
    unsigned int u = c.u;
    unsigned int r = (u + 0x7fffu + ((u >> 16) & 1u)) >> 16;
    return (unsigned short)r;
}
__device__ __forceinline__ float bf2f(unsigned short h) {
    union { unsigned int u; float f; } c; c.u = ((unsigned int)h) << 16;
    return c.f;
}

// ======================= small prologue kernels ==============================

__global__ void conv1_k(const float* __restrict__ x, const float* __restrict__ w,
                        const float* __restrict__ b, float* __restrict__ out) {
    int idx = blockIdx.x * TPB + threadIdx.x;
    const int total = 512 * 64 * 26 * 26;
    if (idx >= total) return;
    int ox = idx % 26; int t = idx / 26;
    int oy = t % 26;   t /= 26;
    int co = t % 64;   int n = t / 64;
    const float* xp = x + (size_t)n * 784 + oy * 28 + ox;
    const float* wp = w + co * 9;
    float s = b[co];
#pragma unroll
    for (int ky = 0; ky < 3; ky++)
#pragma unroll
        for (int kx = 0; kx < 3; kx++)
            s += xp[ky * 28 + kx] * wp[ky * 3 + kx];
    out[idx] = s;
}

__global__ void gn_stats_k(const float* __restrict__ x, float* __restrict__ mean,
                           float* __restrict__ rstd, int N, int C, int HW, int G) {
    int gid  = (blockIdx.x * blockDim.x + threadIdx.x) >> 6;
    int lane = threadIdx.x & 63;
    int total = N * G;
    if (gid >= total) return;
    int n = gid / G, g = gid % G;
    int cpg = C / G;
    int gsize = cpg * HW;
    const float* p = x + ((size_t)n * C + (size_t)g * cpg) * HW;
    float s = 0.f, s2 = 0.f;
    for (int i = lane; i < gsize; i += 64) { float v = p[i]; s += v; s2 += v * v; }
#pragma unroll
    for (int off = 32; off; off >>= 1) {
        s  += __shfl_down(s,  off);
        s2 += __shfl_down(s2, off);
    }
    if (lane == 0) {
        float m = s / gsize;
        float var = s2 / gsize - m * m;
        mean[gid] = m;
        rstd[gid] = rsqrtf(var + 1e-5f);
    }
}

__global__ void gn_apply_relu_k(const float* __restrict__ x, float* __restrict__ out,
                                const float* __restrict__ mean, const float* __restrict__ rstd,
                                const float* __restrict__ gw, const float* __restrict__ gb,
                                int N, int C, int HW, int G) {
    int idx = blockIdx.x * TPB + threadIdx.x;
    int total = N * C * HW;
    if (idx >= total) return;
    int c = (idx / HW) % C;
    int n = idx / (HW * C);
    int cpg = C / G;
    int g = c / cpg;
    float m = mean[n * G + g], r = rstd[n * G + g];
    float v = (x[idx] - m) * r * gw[c] + gb[c];
    out[idx] = v > 0.f ? v : 0.f;
}

// prologue weight transpose: w[co][ci][3][3] -> wT[wave][ci][col16][12]
__global__ void wprep_k(const float* __restrict__ w, float* __restrict__ wT) {
    int i = blockIdx.x * TPB + threadIdx.x;
    if (i >= 64 * 64 * 12) return;
    int k = i % 12; int r = i / 12;
    int col = r % 16; r /= 16;
    int ci = r % 64; int wave = r / 64;
    int co = wave * 16 + col;
    wT[i] = (k < 9) ? w[(co * 64 + ci) * 9 + k] : 0.f;
}

// ODE weight split: w[co][ci][3][3] -> hi/lo bf16 B-frag tables
// layout [t:9][ks:2][nt:4][lane:64][8]: lane holds B[k=ks*32+(l>>4)*8+j][co=nt*16+(l&15)]
__global__ void wsplit_k(const float* __restrict__ w, unsigned short* __restrict__ hiT,
                         unsigned short* __restrict__ loT) {
    int i = blockIdx.x * TPB + threadIdx.x;
    if (i >= 9 * 2 * 4 * 64 * 8) return;
    int j = i & 7, l = (i >> 3) & 63, nt = (i >> 9) & 3, ks = (i >> 11) & 1, t = i >> 12;
    int co = nt * 16 + (l & 15);
    int ci = ks * 32 + (l >> 4) * 8 + j;
    float wv = w[(co * 64 + ci) * 9 + t];
    unsigned short hi = f2bf(wv);
    hiT[i] = hi;
    loT[i] = f2bf(wv - bf2f(hi));
}

// ======================= tiled 3x3 conv (prologue) ===========================

#define KC 2
#define WCHUNK (KC * 16 * 12)
#define WREGION (64 * 16 * 12)

template<int STRIDE, bool SKIP>
__global__ __launch_bounds__(256)
void conv_tile_k(const float* __restrict__ in, const float* __restrict__ wT,
                 const float* __restrict__ dw, const float* __restrict__ addend,
                 float* __restrict__ out, float* __restrict__ skipout,
                 int H, int W, int OH, int OW, int TX, int TY) {
    constexpr int IHT = 6 * STRIDE + 3;
    constexpr int IWT = 6 * STRIDE + 3;
    constexpr int IPITCH = (STRIDE == 1) ? 12 : 16;
    constexpr int RSPAN = 4 * STRIDE + 2;

    __shared__ float sin_[64 * IHT * IPITCH];
    __shared__ float wl[4 * WCHUNK];

    int b = blockIdx.x;
    int tx = b % TX; b /= TX;
    int ty = b % TY; int n = b / TY;
    int oy0 = ty * 7, ox0 = tx * 7;
    int iy0 = oy0 * STRIDE - 1, ix0 = ox0 * STRIDE - 1;

    const int t = threadIdx.x;
    const int wave = t >> 6, lane = t & 63;
    const int cb = t >> 4, cbl = cb & 3, slot = t & 15;
    const int row = slot >> 1, half = slot & 1;
    const int crow = (row < 7) ? row : 0;
    const int co0 = cb * 4;
    float* wlw = wl + wave * WCHUNK;

    const float* ip = in + (size_t)n * 64 * H * W;
    for (int i = t; i < 64 * IHT * IPITCH; i += 256) {
        int c = i % IPITCH; int r = (i / IPITCH) % IHT; int ch = i / (IPITCH * IHT);
        int gy = iy0 + r, gx = ix0 + c;
        float v = 0.f;
        if (c < IWT && (unsigned)gy < (unsigned)H && (unsigned)gx < (unsigned)W)
            v = ip[(size_t)ch * H * W + gy * W + gx];
        sin_[i] = v;
    }
    __syncthreads();

    const float* wg = wT + (size_t)wave * WREGION;
    float acc[4][4];
#pragma unroll
    for (int j = 0; j < 4; j++)
#pragma unroll
        for (int px = 0; px < 4; px++) acc[j][px] = 0.f;

    float2 s0, s1, s2v;
    {
        const float2* gp = (const float2*)wg + lane * 3;
        s0 = gp[0]; s1 = gp[1]; s2v = gp[2];
    }
    for (int ch = 0; ch < 64 / KC; ch++) {
        {
            float2* wp = (float2*)wlw + lane * 3;
            wp[0] = s0; wp[1] = s1; wp[2] = s2v;
        }
        if (ch < 64 / KC - 1) {
            const float2* gp = (const float2*)(wg + (ch + 1) * WCHUNK) + lane * 3;
            s0 = gp[0]; s1 = gp[1]; s2v = gp[2];
        }
        float wr[KC][4][9];
#pragma unroll
        for (int c2 = 0; c2 < KC; c2++)
#pragma unroll
            for (int j = 0; j < 4; j++) {
                const float* wp2 = wlw + (c2 * 16 + cbl * 4 + j) * 12;
                float4 wa = *(const float4*)wp2;
                float4 wb = *(const float4*)(wp2 + 4);
                wr[c2][j][0] = wa.x; wr[c2][j][1] = wa.y; wr[c2][j][2] = wa.z;
                wr[c2][j][3] = wa.w; wr[c2][j][4] = wb.x; wr[c2][j][5] = wb.y;
                wr[c2][j][6] = wb.z; wr[c2][j][7] = wb.w; wr[c2][j][8] = wp2[8];
            }
#pragma unroll
        for (int c2 = 0; c2 < KC; c2++) {
            const float* hc = sin_ + ((ch * KC + c2) * IHT + crow * STRIDE) * IPITCH
                            + half * 4 * STRIDE;
            float rr[3][RSPAN];
#pragma unroll
            for (int ky = 0; ky < 3; ky++) {
                const float* bp = hc + ky * IPITCH;
                if constexpr (STRIDE == 1) {
                    float4 a = *(const float4*)bp; float2 bb = *(const float2*)(bp + 4);
                    rr[ky][0] = a.x; rr[ky][1] = a.y; rr[ky][2] = a.z; rr[ky][3] = a.w;
                    rr[ky][4] = bb.x; rr[ky][5] = bb.y;
                } else {
                    float4 a = *(const float4*)bp; float4 bb = *(const float4*)(bp + 4);
                    float2 cc = *(const float2*)(bp + 8);
                    rr[ky][0] = a.x; rr[ky][1] = a.y; rr[ky][2] = a.z; rr[ky][3] = a.w;
                    rr[ky][4] = bb.x; rr[ky][5] = bb.y; rr[ky][6] = bb.z; rr[ky][7] = bb.w;
                    rr[ky][8] = cc.x; rr[ky][9] = cc.y;
                }
            }
#pragma unroll
            for (int j = 0; j < 4; j++)
#pragma unroll
                for (int px = 0; px < 4; px++) {
                    float s = acc[j][px];
#pragma unroll
                    for (int ky = 0; ky < 3; ky++) {
                        s = fmaf(rr[ky][px * STRIDE + 0], wr[c2][j][ky * 3 + 0], s);
                        s = fmaf(rr[ky][px * STRIDE + 1], wr[c2][j][ky * 3 + 1], s);
                        s = fmaf(rr[ky][px * STRIDE + 2], wr[c2][j][ky * 3 + 2], s);
                    }
                    acc[j][px] = s;
                }
        }
    }

    if constexpr (SKIP) {
        if (slot < 14) {
            float sk[4][4];
#pragma unroll
            for (int j = 0; j < 4; j++)
#pragma unroll
                for (int px = 0; px < 4; px++) sk[j][px] = 0.f;
            for (int ci = 0; ci < 64; ci++) {
                const float* sp = sin_ + (ci * IHT + 2 * row + 1) * IPITCH + half * 8 + 1;
                float xv[4];
#pragma unroll
                for (int px = 0; px < 4; px++) xv[px] = sp[px * 2];
#pragma unroll
                for (int j = 0; j < 4; j++) {
                    float wv = dw[(co0 + j) * 64 + ci];
#pragma unroll
                    for (int px = 0; px < 4; px++) sk[j][px] = fmaf(xv[px], wv, sk[j][px]);
                }
            }
#pragma unroll
            for (int j = 0; j < 4; j++)
#pragma unroll
                for (int px = 0; px < 4; px++) {
                    int oy = oy0 + row, ox = ox0 + half * 4 + px;
                    if (oy < OH && ox < OW && half * 4 + px < 7)
                        skipout[(((size_t)n * 64 + co0 + j) * OH + oy) * OW + ox] = sk[j][px];
                }
        }
    }

    if (slot < 14) {
#pragma unroll
        for (int j = 0; j < 4; j++)
#pragma unroll
            for (int px = 0; px < 4; px++) {
                int oy = oy0 + row, ox = ox0 + half * 4 + px;
                if (oy < OH && ox < OW && half * 4 + px < 7) {
                    size_t idx = (((size_t)n * 64 + co0 + j) * OH + oy) * OW + ox;
                    float v = acc[j][px];
                    if (addend) v += addend[idx];
                    out[idx] = v;
                }
            }
    }
}

// ======================= ODE MFMA mega-kernel ================================
// Accumulators are four NAMED f32x4 locals (a0..a3) via macros — never an
// array, never address-taken — so they live in VGPRs (R5's array-by-pointer
// lambda spilled to scratch: 127 MB WRITE_SIZE). CONV_MFMA declares a local
// `hp` so the nested CONV_TAP macro resolves it lexically (R6 compile fix).

#define HP_PITCH 72          // ushorts per pixel-slot (144 B)
#define ZP 52                // fp32 state pitch per channel

// one tap-GEMM pair (hi+lo) for one m-tile accumulator
#define CONV_TAP(areg, hbase)                                                   \
    {                                                                           \
        int hr_ = min((hbase) + toff, 81);                                      \
        short8 a_ = *(const short8*)(hp + hr_ * HP_PITCH + kq);                 \
        areg = __builtin_amdgcn_mfma_f32_16x16x32_bf16(a_, vbh, areg, 0, 0, 0); \
        areg = __builtin_amdgcn_mfma_f32_16x16x32_bf16(a_, vbl, areg, 0, 0, 0); \
    }

// full 3x3x64->16co conv for this wave: leaves results in a0..a3
#define CONV_MFMA(hpsrc, bhT, blT)                                              \
    a0 = (f32x4){0.f, 0.f, 0.f, 0.f}; a1 = a0; a2 = a0; a3 = a0;                \
    {                                                                           \
        const unsigned short* hp = (hpsrc);                                     \
        const short8* bh_ = (const short8*)(bhT);                               \
        const short8* bl_ = (const short8*)(blT);                               \
        _Pragma("unroll")                                                       \
        for (int t9 = 0; t9 < 9; t9++) {                                        \
            const int toff = (t9 / 3) * 9 + (t9 % 3) - 10;                      \
            _Pragma("unroll")                                                   \
            for (int ks = 0; ks < 2; ks++) {                                    \
                int fidx = ((t9 * 2 + ks) * 4 + nt) * 64 + lane;                \
                short8 vbh = bh_[fidx];                                         \
                short8 vbl = bl_[fidx];                                         \
                int kq = ks * 32 + kq0;                                         \
                CONV_TAP(a0, h0)                                                \
                CONV_TAP(a1, h1)                                                \
                CONV_TAP(a2, h2)                                                \
                CONV_TAP(a3, h3)                                                \
            }                                                                   \
        }                                                                       \
    }

// accumulate GN stats over one m-tile accumulator
#define GN2_ACCUM(areg, mm)                                                     \
    _Pragma("unroll")                                                           \
    for (int j = 0; j < 4; j++) {                                               \
        int p_ = (mm) * 16 + q * 4 + j;                                         \
        if (p_ < 49) { float x_ = areg[j]; s += x_; s2 += x_ * x_; }            \
    }

#define GN2_STORE(areg, mm)                                                     \
    _Pragma("unroll")                                                           \
    for (int j = 0; j < 4; j++) {                                               \
        int p_ = (mm) * 16 + q * 4 + j;                                         \
        if (p_ < 49) {                                                          \
            float y_ = fmaxf(areg[j] * sc + sh, 0.f);                           \
            int hr_ = (p_ / 7 + 1) * 9 + (p_ % 7) + 1;                          \
            hp2[hr_ * HP_PITCH + co] = f2bf(y_);                                \
        }                                                                       \
    }

#define RK4_EPILOGUE(areg, mm)                                                  \
    {                                                                           \
        int pb_ = (mm) * 16 + q * 4;                                            \
        if (pb_ < 49) {                                                         \
            f32x4 sv = *(const f32x4*)(src + rowb + pb_);                       \
            f32x4 zv = (e == 0) ? sv : *(const f32x4*)(z + rowb + pb_);         \
            f32x4 kv;                                                           \
            _Pragma("unroll")                                                   \
            for (int j = 0; j < 4; j++) kv[j] = areg[j] + sv[j];                \
            f32x4 zo = (e == 0) ? zv : *(const f32x4*)(zn + rowb + pb_);        \
            _Pragma("unroll")                                                   \
            for (int j = 0; j < 4; j++) zo[j] += ck * kv[j];                    \
            *(f32x4*)(zn + rowb + pb_) = zo;                                    \
            if (e < 3) {                                                        \
                f32x4 uo;                                                       \
                _Pragma("unroll")                                               \
                for (int j = 0; j < 4; j++) uo[j] = zv[j] + cu * kv[j];         \
                *(f32x4*)(ubuf + rowb + pb_) = uo;                              \
            }                                                                   \
        }                                                                       \
    }

__global__ __launch_bounds__(256, 2)
void ode_mfma_k(const float* __restrict__ z0g,
                const unsigned short* __restrict__ wb1h, const unsigned short* __restrict__ wb1l,
                const unsigned short* __restrict__ wb2h, const unsigned short* __restrict__ wb2l,
                const float* __restrict__ g1w, const float* __restrict__ g1b,
                const float* __restrict__ g2w, const float* __restrict__ g2b,
                const float* __restrict__ fgw, const float* __restrict__ fgb,
                const float* __restrict__ fcw, const float* __restrict__ fcb,
                float* __restrict__ out) {
    __shared__ float zA[64 * ZP], zB[64 * ZP], ubuf[64 * ZP];
    __shared__ unsigned short hp1[82 * HP_PITCH], hp2[82 * HP_PITCH];
    __shared__ float pooled[64];

    const int t = threadIdx.x;
    const int n = blockIdx.x;
    const int lane = t & 63;
    const int nt = t >> 6;                 // wave = N-tile
    const int colL = lane & 15, q = lane >> 4;
    const int co = nt * 16 + colL;
    const int c4 = t >> 2, q4 = t & 3;     // GN1 map

    const float g1wv = g1w[c4], g1bv = g1b[c4];
    const float g2wv = g2w[co], g2bv = g2b[co];

    // per-lane A-row center slots (named, not an array; 1000 = sentinel)
    const int p0 = colL,      h0 = (p0 < 49) ? ((p0 / 7 + 1) * 9 + (p0 % 7) + 1) : 1000;
    const int p1 = 16 + colL, h1 = (p1 < 49) ? ((p1 / 7 + 1) * 9 + (p1 % 7) + 1) : 1000;
    const int p2 = 32 + colL, h2 = (p2 < 49) ? ((p2 / 7 + 1) * 9 + (p2 % 7) + 1) : 1000;
    const int p3 = 48 + colL, h3 = (p3 < 49) ? ((p3 / 7 + 1) * 9 + (p3 % 7) + 1) : 1000;
    const int kq0 = q * 8;

    // ---- init ----
    for (int i = t; i < 64 * ZP; i += 256) { zA[i] = 0.f; zB[i] = 0.f; ubuf[i] = 0.f; }
    for (int i = t; i < 82 * HP_PITCH; i += 256) { hp1[i] = 0; hp2[i] = 0; }
    __syncthreads();
    for (int i = t; i < 3136; i += 256) {
        int c = i / 49, p = i % 49;
        zA[c * ZP + p] = z0g[(size_t)n * 3136 + i];
    }
    __syncthreads();

    float* z  = zA;
    float* zn = zB;
    const float dt = 0.5f;

#pragma unroll 1
    for (int step = 0; step < 12; step++) {
#pragma unroll 1
        for (int e = 0; e < 4; e++) {
            const float ck = (e == 0 || e == 3) ? dt / 6.f : dt / 3.f;
            const float cu = (e == 2) ? dt : 0.5f * dt;
            const float* src = (e == 0) ? z : ubuf;

            // ---- GN1(groups=64)+ReLU: src -> hp1 (bf16, halo layout) ----
            {
                float v[13], s = 0.f, s2 = 0.f;
#pragma unroll
                for (int i = 0; i < 13; i++) {
                    int p = q4 + i * 4;
                    float x = (p < 49) ? src[c4 * ZP + p] : 0.f;
                    v[i] = x; s += x; s2 += x * x;
                }
                s += __shfl_xor(s, 1); s2 += __shfl_xor(s2, 1);
                s += __shfl_xor(s, 2); s2 += __shfl_xor(s2, 2);
                float mu = s * (1.f / 49.f);
                float r = rsqrtf(s2 * (1.f / 49.f) - mu * mu + 1e-5f);
                float sc = r * g1wv, sh = g1bv - mu * sc;
#pragma unroll
                for (int i = 0; i < 13; i++) {
                    int p = q4 + i * 4;
                    if (p < 49) {
                        float y = fmaxf(v[i] * sc + sh, 0.f);
                        int hr = (p / 7 + 1) * 9 + (p % 7) + 1;
                        hp1[hr * HP_PITCH + c4] = f2bf(y);
                    }
                }
            }
            __syncthreads();

            // ---- conv1 + in-register GN2(groups=64)+ReLU -> hp2 ----
            {
                f32x4 a0, a1, a2, a3;
                CONV_MFMA(hp1, wb1h, wb1l)

                float s = 0.f, s2 = 0.f;
                GN2_ACCUM(a0, 0) GN2_ACCUM(a1, 1) GN2_ACCUM(a2, 2) GN2_ACCUM(a3, 3)
                s += __shfl_xor(s, 16); s2 += __shfl_xor(s2, 16);
                s += __shfl_xor(s, 32); s2 += __shfl_xor(s2, 32);
                float mu = s * (1.f / 49.f);
                float r = rsqrtf(s2 * (1.f / 49.f) - mu * mu + 1e-5f);
                float sc = r * g2wv, sh = g2bv - mu * sc;
                GN2_STORE(a0, 0) GN2_STORE(a1, 1) GN2_STORE(a2, 2) GN2_STORE(a3, 3)
            }
            __syncthreads();

            // ---- conv2 + RK4 epilogue ----
            {
                f32x4 a0, a1, a2, a3;
                CONV_MFMA(hp2, wb2h, wb2l)

                const int rowb = co * ZP;
                RK4_EPILOGUE(a0, 0) RK4_EPILOGUE(a1, 1)
                RK4_EPILOGUE(a2, 2) RK4_EPILOGUE(a3, 3)
            }
            __syncthreads();
        }
        float* tmp = z; z = zn; zn = tmp;
    }

    // ---- final GN(groups=32)+ReLU + mean-pool ----
    {
        float v[13], s = 0.f, s2 = 0.f;
#pragma unroll
        for (int i = 0; i < 13; i++) {
            int p = q4 + i * 4;
            float x = (p < 49) ? z[c4 * ZP + p] : 0.f;
            v[i] = x; s += x; s2 += x * x;
        }
        s += __shfl_xor(s, 1); s2 += __shfl_xor(s2, 1);
        s += __shfl_xor(s, 2); s2 += __shfl_xor(s2, 2);
        s += __shfl_xor(s, 4); s2 += __shfl_xor(s2, 4);   // pair channels (G=32)
        float mu = s * (1.f / 98.f);
        float r = rsqrtf(s2 * (1.f / 98.f) - mu * mu + 1e-5f);
        float sc = r * fgw[c4], sh = fgb[c4] - mu * sc;
        float ps = 0.f;
#pragma unroll
        for (int i = 0; i < 13; i++) {
            int p = q4 + i * 4;
            if (p < 49) ps += fmaxf(v[i] * sc + sh, 0.f);
        }
        ps += __shfl_xor(ps, 1);
        ps += __shfl_xor(ps, 2);
        if (q4 == 0) pooled[c4] = ps * (1.f / 49.f);
    }
    __syncthreads();
    if (t < 10) {
        float a = fcb[t];
#pragma unroll
        for (int k = 0; k < 64; k++) a += pooled[k] * fcw[t * 64 + k];
        out[(size_t)n * 10 + t] = a;
    }
}

static inline int nblk(long long total) { return (int)((total + TPB - 1) / TPB); }

extern "C" void kernel_launch(void* const* d_in, const int* in_sizes, int n_in,
                              void* d_out, int out_size, void* d_ws, size_t ws_size,
                              hipStream_t stream) {
    const float* x       = (const float*)d_in[0];
    const float* conv1_w = (const float*)d_in[1];
    const float* conv1_b = (const float*)d_in[2];
    const float* r1_g1w  = (const float*)d_in[3];
    const float* r1_g1b  = (const float*)d_in[4];
    const float* r1_c1w  = (const float*)d_in[5];
    const float* r1_g2w  = (const float*)d_in[6];
    const float* r1_g2b  = (const float*)d_in[7];
    const float* r1_c2w  = (const float*)d_in[8];
    const float* r1_dw   = (const float*)d_in[9];
    const float* r2_g1w  = (const float*)d_in[10];
    const float* r2_g1b  = (const float*)d_in[11];
    const float* r2_c1w  = (const float*)d_in[12];
    const float* r2_g2w  = (const float*)d_in[13];
    const float* r2_g2b  = (const float*)d_in[14];
    const float* r2_c2w  = (const float*)d_in[15];
    const float* r2_dw   = (const float*)d_in[16];
    const float* o_g1w   = (const float*)d_in[17];
    const float* o_g1b   = (const float*)d_in[18];
    const float* o_c1w   = (const float*)d_in[19];
    const float* o_g2w   = (const float*)d_in[20];
    const float* o_g2b   = (const float*)d_in[21];
    const float* o_c2w   = (const float*)d_in[22];
    const float* fin_gw  = (const float*)d_in[23];
    const float* fin_gb  = (const float*)d_in[24];
    const float* fc_w    = (const float*)d_in[25];
    const float* fc_b    = (const float*)d_in[26];
    float* out = (float*)d_out;

    const int N = 512;
    const long long SZ26 = 512LL * 64 * 26 * 26;
    const long long SZ13 = 512LL * 64 * 13 * 13;
    const long long SZ7  = 512LL * 64 * 7 * 7;
    const long long WTS  = 64 * 64 * 12;
    const long long WBS  = 9 * 2 * 4 * 64 * 8;     // 36864 ushorts per table

    float* B26   = (float*)d_ws;
    float* A13   = B26 + SZ26;
    float* B13   = A13 + SZ13;
    float* Z7    = B13 + SZ13;
    float* U7    = Z7 + SZ7;
    float* MEAN  = U7 + SZ7;
    float* RSTD  = MEAN + 512 * 64;
    float* WTr11 = RSTD + 512 * 64;
    float* WTr12 = WTr11 + WTS;
    float* WTr21 = WTr12 + WTS;
    float* WTr22 = WTr21 + WTS;
    unsigned short* WB1h = (unsigned short*)(WTr22 + WTS);
    unsigned short* WB1l = WB1h + WBS;
    unsigned short* WB2h = WB1l + WBS;
    unsigned short* WB2l = WB2h + WBS;

    auto gn = [&](const float* src, float* dst, int HW, int G,
                  const float* gw, const float* gb) {
        int waves = N * G;
        gn_stats_k<<<nblk((long long)waves * 64), TPB, 0, stream>>>(src, MEAN, RSTD, N, 64, HW, G);
        gn_apply_relu_k<<<nblk((long long)N * 64 * HW), TPB, 0, stream>>>(
            src, dst, MEAN, RSTD, gw, gb, N, 64, HW, G);
    };

    // ---- weight prep ----
    wprep_k<<<nblk(WTS), TPB, 0, stream>>>(r1_c1w, WTr11);
    wprep_k<<<nblk(WTS), TPB, 0, stream>>>(r1_c2w, WTr12);
    wprep_k<<<nblk(WTS), TPB, 0, stream>>>(r2_c1w, WTr21);
    wprep_k<<<nblk(WTS), TPB, 0, stream>>>(r2_c2w, WTr22);
    wsplit_k<<<nblk(WBS), TPB, 0, stream>>>(o_c1w, WB1h, WB1l);
    wsplit_k<<<nblk(WBS), TPB, 0, stream>>>(o_c2w, WB2h, WB2l);

    // ---- stage 0: conv1 ----
    conv1_k<<<nblk(SZ26), TPB, 0, stream>>>(x, conv1_w, conv1_b, B26);

    // ---- residual block 1: 26x26 -> 13x13 ----
    gn(B26, B26, 676, 32, r1_g1w, r1_g1b);
    conv_tile_k<2, true><<<512 * 4, 256, 0, stream>>>(B26, WTr11, r1_dw, nullptr,
                                                      A13, B13, 26, 26, 13, 13, 2, 2);
    gn(A13, A13, 169, 32, r1_g2w, r1_g2b);
    conv_tile_k<1, false><<<512 * 4, 256, 0, stream>>>(A13, WTr12, nullptr, B13,
                                                       B13, nullptr, 13, 13, 13, 13, 2, 2);

    // ---- residual block 2: 13x13 -> 7x7 ----
    gn(B13, B13, 169, 32, r2_g1w, r2_g1b);
    conv_tile_k<2, true><<<512, 256, 0, stream>>>(B13, WTr21, r2_dw, nullptr,
                                                  U7, Z7, 13, 13, 7, 7, 1, 1);
    gn(U7, U7, 49, 32, r2_g2w, r2_g2b);
    conv_tile_k<1, false><<<512, 256, 0, stream>>>(U7, WTr22, nullptr, Z7,
                                                   Z7, nullptr, 7, 7, 7, 7, 1, 1);

    // ---- fused MFMA ODE (12 RK4 steps) + final GN + pool + FC ----
    ode_mfma_k<<<512, 256, 0, stream>>>(Z7, WB1h, WB1l, WB2h, WB2l,
                                        o_g1w, o_g1b, o_g2w, o_g2b,
                                        fin_gw, fin_gb, fc_w, fc_b, out);
}